// Round 1
// baseline (1498.777 us; speedup 1.0000x reference)
//
#include <hip/hip_runtime.h>
#include <math.h>

#define BB 8
#define LQ 2048
#define LA 2048
#define DD 300
#define HHH 150
#define NROWS (BB * LQ)   // 16384 rows for Q-side and A-side each

// ---------------------------------------------------------------------------
// Gate projection: Out[r][h] = sigmoid(X@Wi + bi)[r][h] * tanh(X@Wu + bu)[r][h]
// X: [nrows x 300], Wi/Wu: [300 x 150]. Block: 256 thr, tile 64 rows x 150 h.
// K staged in two 150-chunks to keep LDS under 64 KB.
// ---------------------------------------------------------------------------
__global__ __launch_bounds__(256) void gate_kernel(
    const float* __restrict__ X,
    const float* __restrict__ Wi, const float* __restrict__ Wu,
    const float* __restrict__ bi, const float* __restrict__ bu,
    float* __restrict__ Out)
{
    __shared__ float Xs[64][153];   // stride 153: odd-ish, avoids 4-way bank conflicts
    const int r0 = blockIdx.x * 64;
    const int tid = threadIdx.x;
    const int c = tid & 15;        // h-group
    const int rg = tid >> 4;       // row-group 0..15; thread owns rows rg+16m

    float acc_i[4][10], acc_u[4][10];
#pragma unroll
    for (int m = 0; m < 4; m++)
#pragma unroll
        for (int k = 0; k < 10; k++) { acc_i[m][k] = 0.f; acc_u[m][k] = 0.f; }

    for (int dc = 0; dc < 2; dc++) {
        for (int i = tid; i < 64 * 150; i += 256) {
            int row = i / 150, col = i - row * 150;
            Xs[row][col] = X[(size_t)(r0 + row) * DD + dc * 150 + col];
        }
        __syncthreads();
        for (int d = 0; d < 150; d++) {
            float xv[4];
#pragma unroll
            for (int m = 0; m < 4; m++) xv[m] = Xs[rg + 16 * m][d];
            const int gd = dc * 150 + d;
#pragma unroll
            for (int k = 0; k < 10; k++) {
                int h = c + 16 * k;
                int hc = h < HHH ? h : (HHH - 1);   // clamp; result discarded later
                float wi = Wi[(size_t)gd * HHH + hc];
                float wu = Wu[(size_t)gd * HHH + hc];
#pragma unroll
                for (int m = 0; m < 4; m++) {
                    acc_i[m][k] = fmaf(xv[m], wi, acc_i[m][k]);
                    acc_u[m][k] = fmaf(xv[m], wu, acc_u[m][k]);
                }
            }
        }
        __syncthreads();
    }

#pragma unroll
    for (int k = 0; k < 10; k++) {
        int h = c + 16 * k;
        if (h >= HHH) continue;
        float bih = bi[h], buh = bu[h];
#pragma unroll
        for (int m = 0; m < 4; m++) {
            float xi = acc_i[m][k] + bih;
            float xu = acc_u[m][k] + buh;
            float s = 1.f / (1.f + __expf(-xi));
            float t = tanhf(xu);
            Out[(size_t)(r0 + rg + 16 * m) * HHH + h] = s * t;
        }
    }
}

// ---------------------------------------------------------------------------
// Qg = Qh @ Wg + bg   (K = 150, N = 150)
// ---------------------------------------------------------------------------
__global__ __launch_bounds__(256) void projg_kernel(
    const float* __restrict__ Xh,
    const float* __restrict__ Wg, const float* __restrict__ bg,
    float* __restrict__ Out)
{
    __shared__ float Xs[64][153];
    const int r0 = blockIdx.x * 64;
    const int tid = threadIdx.x;
    const int c = tid & 15;
    const int rg = tid >> 4;

    float acc[4][10];
#pragma unroll
    for (int m = 0; m < 4; m++)
#pragma unroll
        for (int k = 0; k < 10; k++) acc[m][k] = 0.f;

    for (int i = tid; i < 64 * 150; i += 256) {
        int row = i / 150, col = i - row * 150;
        Xs[row][col] = Xh[(size_t)(r0 + row) * HHH + col];
    }
    __syncthreads();
    for (int d = 0; d < 150; d++) {
        float xv[4];
#pragma unroll
        for (int m = 0; m < 4; m++) xv[m] = Xs[rg + 16 * m][d];
#pragma unroll
        for (int k = 0; k < 10; k++) {
            int h = c + 16 * k;
            int hc = h < HHH ? h : (HHH - 1);
            float w = Wg[(size_t)d * HHH + hc];
#pragma unroll
            for (int m = 0; m < 4; m++) acc[m][k] = fmaf(xv[m], w, acc[m][k]);
        }
    }

#pragma unroll
    for (int k = 0; k < 10; k++) {
        int h = c + 16 * k;
        if (h >= HHH) continue;
        float bgh = bg[h];
#pragma unroll
        for (int m = 0; m < 4; m++)
            Out[(size_t)(r0 + rg + 16 * m) * HHH + h] = acc[m][k] + bgh;
    }
}

// ---------------------------------------------------------------------------
// Flash attention over q:  S[a][q] = Ah[a]·Qg[q]; P = softmax_q(S);
// Hm[a] = sum_q P[a][q] * Qh[q].   One block = (b, 32 a-rows); TQ = 32.
// Thread (ta,tq): owns a-rows {ta, ta+16}, S-cols {tq, tq+16}, h-cols tq+16k.
// ---------------------------------------------------------------------------
__global__ __launch_bounds__(256) void attn_kernel(
    const float* __restrict__ Qg, const float* __restrict__ Qh,
    const float* __restrict__ Ah, float* __restrict__ Hm)
{
    __shared__ float AhS[32][153];
    __shared__ float QgS[32][153];
    __shared__ float QhS[32][153];
    __shared__ float Ss[32][33];

    const int b = blockIdx.y;
    const int a0 = blockIdx.x * 32;
    const int tid = threadIdx.x;
    const int tq = tid & 15;
    const int ta = tid >> 4;

    const float* AhB = Ah + (size_t)b * LA * HHH;
    const float* QgB = Qg + (size_t)b * LQ * HHH;
    const float* QhB = Qh + (size_t)b * LQ * HHH;

    for (int i = tid; i < 32 * 150; i += 256) {
        int row = i / 150, col = i - row * 150;
        AhS[row][col] = AhB[(size_t)(a0 + row) * HHH + col];
    }

    float m_r[2] = { -INFINITY, -INFINITY };
    float l_r[2] = { 0.f, 0.f };
    float acc[2][10];
#pragma unroll
    for (int i2 = 0; i2 < 2; i2++)
#pragma unroll
        for (int k = 0; k < 10; k++) acc[i2][k] = 0.f;

    for (int q0 = 0; q0 < LQ; q0 += 32) {
        __syncthreads();   // protect QgS/QhS/Ss from previous iter readers; AhS visibility on first iter
        for (int i = tid; i < 32 * 150; i += 256) {
            int row = i / 150, col = i - row * 150;
            QgS[row][col] = QgB[(size_t)(q0 + row) * HHH + col];
            QhS[row][col] = QhB[(size_t)(q0 + row) * HHH + col];
        }
        __syncthreads();

        // ---- scores: 2x2 micro-tile ----
        float s00 = 0.f, s01 = 0.f, s10 = 0.f, s11 = 0.f;
        for (int d = 0; d < 150; d++) {
            float a0v = AhS[ta][d], a1v = AhS[ta + 16][d];
            float q0v = QgS[tq][d], q1v = QgS[tq + 16][d];
            s00 = fmaf(a0v, q0v, s00); s01 = fmaf(a0v, q1v, s01);
            s10 = fmaf(a1v, q0v, s10); s11 = fmaf(a1v, q1v, s11);
        }
        Ss[ta][tq] = s00;      Ss[ta][tq + 16] = s01;
        Ss[ta + 16][tq] = s10; Ss[ta + 16][tq + 16] = s11;
        __syncthreads();

        // ---- online softmax update for both owned rows ----
        float p0[32], p1[32];
        float tmax0 = -INFINITY, tmax1 = -INFINITY;
#pragma unroll
        for (int j = 0; j < 32; j++) {
            p0[j] = Ss[ta][j];      tmax0 = fmaxf(tmax0, p0[j]);
            p1[j] = Ss[ta + 16][j]; tmax1 = fmaxf(tmax1, p1[j]);
        }
        float mn0 = fmaxf(m_r[0], tmax0);
        float mn1 = fmaxf(m_r[1], tmax1);
        float al0 = __expf(m_r[0] - mn0);
        float al1 = __expf(m_r[1] - mn1);
        float sum0 = 0.f, sum1 = 0.f;
#pragma unroll
        for (int j = 0; j < 32; j++) {
            p0[j] = __expf(p0[j] - mn0); sum0 += p0[j];
            p1[j] = __expf(p1[j] - mn1); sum1 += p1[j];
        }
        m_r[0] = mn0; m_r[1] = mn1;
        l_r[0] = l_r[0] * al0 + sum0;
        l_r[1] = l_r[1] * al1 + sum1;

#pragma unroll
        for (int k = 0; k < 10; k++) {
            int h = tq + 16 * k;
            int hc = h < HHH ? h : (HHH - 1);
            float t0 = 0.f, t1 = 0.f;
#pragma unroll
            for (int j = 0; j < 32; j++) {
                float v = QhS[j][hc];
                t0 = fmaf(p0[j], v, t0);
                t1 = fmaf(p1[j], v, t1);
            }
            acc[0][k] = acc[0][k] * al0 + t0;
            acc[1][k] = acc[1][k] * al1 + t1;
        }
    }

    // ---- store normalized output ----
#pragma unroll
    for (int i2 = 0; i2 < 2; i2++) {
        int ar = a0 + ta + 16 * i2;
        float inv = 1.f / l_r[i2];
#pragma unroll
        for (int k = 0; k < 10; k++) {
            int h = tq + 16 * k;
            if (h < HHH)
                Hm[((size_t)b * LA + ar) * HHH + h] = acc[i2][k] * inv;
        }
    }
}

// ---------------------------------------------------------------------------
// Final: Out = relu(concat([Ah, Hm], -1) @ Wt + bt)
// Wt: [300 x 150]; rows 0..149 hit Ah, rows 150..299 hit Hm.
// ---------------------------------------------------------------------------
__global__ __launch_bounds__(256) void final_kernel(
    const float* __restrict__ Ah, const float* __restrict__ Hm,
    const float* __restrict__ Wt, const float* __restrict__ bt,
    float* __restrict__ Out)
{
    __shared__ float Xs[64][153];
    const int r0 = blockIdx.x * 64;
    const int tid = threadIdx.x;
    const int c = tid & 15;
    const int rg = tid >> 4;

    float acc[4][10];
#pragma unroll
    for (int m = 0; m < 4; m++)
#pragma unroll
        for (int k = 0; k < 10; k++) acc[m][k] = 0.f;

    for (int half = 0; half < 2; half++) {
        const float* src = half ? Hm : Ah;
        for (int i = tid; i < 64 * 150; i += 256) {
            int row = i / 150, col = i - row * 150;
            Xs[row][col] = src[(size_t)(r0 + row) * HHH + col];
        }
        __syncthreads();
        for (int d = 0; d < 150; d++) {
            float xv[4];
#pragma unroll
            for (int m = 0; m < 4; m++) xv[m] = Xs[rg + 16 * m][d];
            const int gd = half * 150 + d;
#pragma unroll
            for (int k = 0; k < 10; k++) {
                int h = c + 16 * k;
                int hc = h < HHH ? h : (HHH - 1);
                float w = Wt[(size_t)gd * HHH + hc];
#pragma unroll
                for (int m = 0; m < 4; m++) acc[m][k] = fmaf(xv[m], w, acc[m][k]);
            }
        }
        __syncthreads();
    }

#pragma unroll
    for (int k = 0; k < 10; k++) {
        int h = c + 16 * k;
        if (h >= HHH) continue;
        float bth = bt[h];
#pragma unroll
        for (int m = 0; m < 4; m++) {
            float v = acc[m][k] + bth;
            Out[(size_t)(r0 + rg + 16 * m) * HHH + h] = v > 0.f ? v : 0.f;
        }
    }
}

// ---------------------------------------------------------------------------
extern "C" void kernel_launch(void* const* d_in, const int* in_sizes, int n_in,
                              void* d_out, int out_size, void* d_ws, size_t ws_size,
                              hipStream_t stream)
{
    const float* Q  = (const float*)d_in[0];
    const float* A  = (const float*)d_in[1];
    const float* Wi = (const float*)d_in[2];
    const float* Wu = (const float*)d_in[3];
    const float* Wg = (const float*)d_in[4];
    const float* Wt = (const float*)d_in[5];
    const float* bi = (const float*)d_in[6];
    const float* bu = (const float*)d_in[7];
    const float* bg = (const float*)d_in[8];
    const float* bt = (const float*)d_in[9];
    float* out = (float*)d_out;

    float* ws  = (float*)d_ws;
    const size_t SZ = (size_t)BB * LA * HHH;   // 2,457,600 floats per array
    float* Qh  = ws;
    float* Ahw = ws + SZ;
    float* Qg  = ws + 2 * SZ;
    float* Hm  = ws + 3 * SZ;

    gate_kernel<<<NROWS / 64, 256, 0, stream>>>(Q, Wi, Wu, bi, bu, Qh);
    gate_kernel<<<NROWS / 64, 256, 0, stream>>>(A, Wi, Wu, bi, bu, Ahw);
    projg_kernel<<<NROWS / 64, 256, 0, stream>>>(Qh, Wg, bg, Qg);
    attn_kernel<<<dim3(LA / 32, BB), 256, 0, stream>>>(Qg, Qh, Ahw, Hm);
    final_kernel<<<NROWS / 64, 256, 0, stream>>>(Ahw, Hm, Wt, bt, out);
}

// Round 2
// 482.605 us; speedup vs baseline: 3.1056x; 3.1056x over previous
//
#include <hip/hip_runtime.h>
#include <math.h>

#define BB 8
#define LQ 2048
#define LA 2048
#define DD 300
#define HHH 150
#define NROWS (BB * LQ)

// padded bf16 layouts
#define KP 168          // padded d/h stride for Ah_bf16 / Qg_bf16 (bytes: 336 = 21*16)
#define QS 72           // q-stride for QhT tiles and PS (144 B)
#define HP 160          // padded h rows in QhT tiles

typedef __bf16 bf16x8 __attribute__((ext_vector_type(8)));
typedef float f32x4 __attribute__((ext_vector_type(4)));

__device__ __forceinline__ void gl_lds16(const void* g, void* l) {
    __builtin_amdgcn_global_load_lds(
        (const __attribute__((address_space(1))) void*)g,
        (__attribute__((address_space(3))) void*)l,
        16, 0, 0);
}

// ---------------------------------------------------------------------------
// Gate: Out = sigmoid(X@Wi+bi)*tanh(X@Wu+bu); fp32 out + optional padded bf16
// ---------------------------------------------------------------------------
__global__ __launch_bounds__(256) void gate_kernel(
    const float* __restrict__ X,
    const float* __restrict__ Wi, const float* __restrict__ Wu,
    const float* __restrict__ bi, const float* __restrict__ bu,
    float* __restrict__ Out, __bf16* __restrict__ OutBf)
{
    __shared__ float Xs[64][153];
    const int r0 = blockIdx.x * 64;
    const int tid = threadIdx.x;
    const int c = tid & 15;
    const int rg = tid >> 4;

    float acc_i[4][10], acc_u[4][10];
#pragma unroll
    for (int m = 0; m < 4; m++)
#pragma unroll
        for (int k = 0; k < 10; k++) { acc_i[m][k] = 0.f; acc_u[m][k] = 0.f; }

    for (int dc = 0; dc < 2; dc++) {
        for (int i = tid; i < 64 * 150; i += 256) {
            int row = i / 150, col = i - row * 150;
            Xs[row][col] = X[(size_t)(r0 + row) * DD + dc * 150 + col];
        }
        __syncthreads();
        for (int d = 0; d < 150; d++) {
            float xv[4];
#pragma unroll
            for (int m = 0; m < 4; m++) xv[m] = Xs[rg + 16 * m][d];
            const int gd = dc * 150 + d;
#pragma unroll
            for (int k = 0; k < 10; k++) {
                int h = c + 16 * k;
                int hc = h < HHH ? h : (HHH - 1);
                float wi = Wi[(size_t)gd * HHH + hc];
                float wu = Wu[(size_t)gd * HHH + hc];
#pragma unroll
                for (int m = 0; m < 4; m++) {
                    acc_i[m][k] = fmaf(xv[m], wi, acc_i[m][k]);
                    acc_u[m][k] = fmaf(xv[m], wu, acc_u[m][k]);
                }
            }
        }
        __syncthreads();
    }

#pragma unroll
    for (int k = 0; k < 10; k++) {
        int h = c + 16 * k;
        int hc = h < HHH ? h : (HHH - 1);
        float bih = bi[hc], buh = bu[hc];
#pragma unroll
        for (int m = 0; m < 4; m++) {
            int row = r0 + rg + 16 * m;
            float xi = acc_i[m][k] + bih;
            float xu = acc_u[m][k] + buh;
            float s = 1.f / (1.f + __expf(-xi));
            float t = tanhf(xu);
            float v = s * t;
            if (h < HHH) {
                Out[(size_t)row * HHH + h] = v;
                if (OutBf) OutBf[(size_t)row * KP + h] = (__bf16)v;
            } else if (OutBf) {
                OutBf[(size_t)row * KP + h] = (__bf16)0.f;  // pad 150..159
            }
        }
    }
    if (OutBf && c < 8) {
#pragma unroll
        for (int m = 0; m < 4; m++)
            OutBf[(size_t)(r0 + rg + 16 * m) * KP + 160 + c] = (__bf16)0.f;
    }
}

// ---------------------------------------------------------------------------
// Qg = Qh @ Wg + bg -> bf16 padded [NROWS][168]
// ---------------------------------------------------------------------------
__global__ __launch_bounds__(256) void projg_kernel(
    const float* __restrict__ Xh,
    const float* __restrict__ Wg, const float* __restrict__ bg,
    __bf16* __restrict__ OutBf)
{
    __shared__ float Xs[64][153];
    const int r0 = blockIdx.x * 64;
    const int tid = threadIdx.x;
    const int c = tid & 15;
    const int rg = tid >> 4;

    float acc[4][10];
#pragma unroll
    for (int m = 0; m < 4; m++)
#pragma unroll
        for (int k = 0; k < 10; k++) acc[m][k] = 0.f;

    for (int i = tid; i < 64 * 150; i += 256) {
        int row = i / 150, col = i - row * 150;
        Xs[row][col] = Xh[(size_t)(r0 + row) * HHH + col];
    }
    __syncthreads();
    for (int d = 0; d < 150; d++) {
        float xv[4];
#pragma unroll
        for (int m = 0; m < 4; m++) xv[m] = Xs[rg + 16 * m][d];
#pragma unroll
        for (int k = 0; k < 10; k++) {
            int h = c + 16 * k;
            int hc = h < HHH ? h : (HHH - 1);
            float w = Wg[(size_t)d * HHH + hc];
#pragma unroll
            for (int m = 0; m < 4; m++) acc[m][k] = fmaf(xv[m], w, acc[m][k]);
        }
    }

#pragma unroll
    for (int k = 0; k < 10; k++) {
        int h = c + 16 * k;
        int hc = h < HHH ? h : (HHH - 1);
        float bgh = bg[hc];
#pragma unroll
        for (int m = 0; m < 4; m++) {
            int row = r0 + rg + 16 * m;
            float v = (h < HHH) ? (acc[m][k] + bgh) : 0.f;
            OutBf[(size_t)row * KP + h] = (__bf16)v;
        }
    }
    if (c < 8) {
#pragma unroll
        for (int m = 0; m < 4; m++)
            OutBf[(size_t)(r0 + rg + 16 * m) * KP + 160 + c] = (__bf16)0.f;
    }
}

// ---------------------------------------------------------------------------
// Transpose Qh fp32 [b][q][150] -> QhT tiles bf16 [b][qt][160][72]
// tile (b,qt): QhT[h][j] = Qh[b][qt*64+j][h], zero-padded h>=150 / j>=64
// ---------------------------------------------------------------------------
__global__ __launch_bounds__(256) void transpose_qh(
    const float* __restrict__ Qh, __bf16* __restrict__ QhT)
{
    __shared__ float T[64][152];
    const int tid = threadIdx.x;
    const int b = blockIdx.y, qt = blockIdx.x;
    const float* src = Qh + ((size_t)b * LQ + qt * 64) * HHH;
    for (int i = tid; i < 64 * 150; i += 256) {
        int j = i / 150, h = i - j * 150;
        T[j][h] = src[i];
    }
    __syncthreads();
    __bf16* dst = QhT + (size_t)(b * 32 + qt) * HP * QS;
    for (int i = tid; i < HP * QS; i += 256) {
        int h = i / QS, j = i - h * QS;
        float v = (h < HHH && j < 64) ? T[j][h] : 0.f;
        dst[i] = (__bf16)v;
    }
}

// ---------------------------------------------------------------------------
// MFMA flash attention (no-max softmax; |S| <= ~6 so exp is safe in fp32)
// block = (a-tile of 64, batch); wave w owns a-rows w*16..w*16+15
// ---------------------------------------------------------------------------
__global__ __launch_bounds__(256, 1) void attn_mfma(
    const __bf16* __restrict__ QgG, const __bf16* __restrict__ AhG,
    const __bf16* __restrict__ QhTG, float* __restrict__ Hm)
{
    __shared__ __align__(16) __bf16 AhS[64 * KP];      // 21504 B
    __shared__ __align__(16) __bf16 QgS[64 * KP];      // 21504 B
    __shared__ __align__(16) __bf16 QhTS[23552 / 2];   // 160x72 (+tail slack)
    __shared__ __align__(16) __bf16 PS[64 * QS];       // 9216 B

    const int tid = threadIdx.x;
    const int w = tid >> 6;
    const int lane = tid & 63;
    const int g = lane >> 4;
    const int n16 = lane & 15;
    const int b = blockIdx.y;
    const int a0 = blockIdx.x * 64;

    // stage Ah tile once (flat copy; global layout == LDS layout, stride 168)
    const char* ahSlab = (const char*)(AhG + ((size_t)b * LA + a0) * KP);
    for (int ofs = w * 1024; ofs < 21504; ofs += 4096)
        gl_lds16(ahSlab + ofs + lane * 16, (char*)AhS + ofs);

    float lsum[4] = {0.f, 0.f, 0.f, 0.f};
    f32x4 acc[10];
#pragma unroll
    for (int t = 0; t < 10; t++) acc[t] = (f32x4){0.f, 0.f, 0.f, 0.f};

    const char* qgBase = (const char*)(QgG + (size_t)b * LQ * KP);
    const char* qhBase = (const char*)(QhTG + (size_t)b * 32 * HP * QS);

    for (int qt = 0; qt < 32; qt++) {
        __syncthreads();  // prev-iter readers done (and AhS vmcnt on iter 0)
        const char* qgSlab = qgBase + (size_t)qt * 64 * (KP * 2);
        for (int ofs = w * 1024; ofs < 21504; ofs += 4096)
            gl_lds16(qgSlab + ofs + lane * 16, (char*)QgS + ofs);
        const char* qhSlab = qhBase + (size_t)qt * (HP * QS * 2);
        for (int ofs = w * 1024; ofs < 23552; ofs += 4096)
            gl_lds16(qhSlab + ofs + lane * 16, (char*)QhTS + ofs);
        __syncthreads();  // staging complete

        // ---- S = Ah(16a) x Qg(64q), K=160 ----
        bf16x8 af[5];
#pragma unroll
        for (int ks = 0; ks < 5; ks++)
            af[ks] = *(const bf16x8*)(AhS + (w * 16 + n16) * KP + ks * 32 + g * 8);
        f32x4 s[4];
#pragma unroll
        for (int t = 0; t < 4; t++) s[t] = (f32x4){0.f, 0.f, 0.f, 0.f};
#pragma unroll
        for (int t = 0; t < 4; t++)
#pragma unroll
            for (int ks = 0; ks < 5; ks++) {
                bf16x8 bf_ = *(const bf16x8*)(QgS + (t * 16 + n16) * KP + ks * 32 + g * 8);
                s[t] = __builtin_amdgcn_mfma_f32_16x16x32_bf16(af[ks], bf_, s[t], 0, 0, 0);
            }

        // ---- P = exp(S); accumulate l; round-trip P through LDS (bf16) ----
#pragma unroll
        for (int t = 0; t < 4; t++)
#pragma unroll
            for (int r = 0; r < 4; r++) {
                float p = __expf(s[t][r]);
                lsum[r] += p;
                PS[(w * 16 + g * 4 + r) * QS + t * 16 + n16] = (__bf16)p;
            }
        // in-wave write->read: compiler inserts lgkmcnt wait; rows are wave-private

        // ---- O += P(16a x 64q) x QhT(64q x 160h) ----
#pragma unroll
        for (int ks = 0; ks < 2; ks++) {
            bf16x8 pf = *(const bf16x8*)(PS + (w * 16 + n16) * QS + ks * 32 + g * 8);
#pragma unroll
            for (int t = 0; t < 10; t++) {
                bf16x8 vf = *(const bf16x8*)(QhTS + (t * 16 + n16) * QS + ks * 32 + g * 8);
                acc[t] = __builtin_amdgcn_mfma_f32_16x16x32_bf16(pf, vf, acc[t], 0, 0, 0);
            }
        }
    }

    // ---- normalize and store ----
    float invl[4];
#pragma unroll
    for (int r = 0; r < 4; r++) {
        float sres = lsum[r];
#pragma unroll
        for (int m = 1; m < 16; m <<= 1) sres += __shfl_xor(sres, m, 64);
        invl[r] = 1.f / sres;
    }
#pragma unroll
    for (int t = 0; t < 10; t++) {
        int h = t * 16 + n16;
        if (h < HHH) {
#pragma unroll
            for (int r = 0; r < 4; r++) {
                int row = a0 + w * 16 + g * 4 + r;
                Hm[((size_t)b * LA + row) * HHH + h] = acc[t][r] * invl[r];
            }
        }
    }
}

// ---------------------------------------------------------------------------
// Final: Out = relu(concat([Ah, Hm]) @ Wt + bt)
// ---------------------------------------------------------------------------
__global__ __launch_bounds__(256) void final_kernel(
    const float* __restrict__ Ah, const float* __restrict__ Hm,
    const float* __restrict__ Wt, const float* __restrict__ bt,
    float* __restrict__ Out)
{
    __shared__ float Xs[64][153];
    const int r0 = blockIdx.x * 64;
    const int tid = threadIdx.x;
    const int c = tid & 15;
    const int rg = tid >> 4;

    float acc[4][10];
#pragma unroll
    for (int m = 0; m < 4; m++)
#pragma unroll
        for (int k = 0; k < 10; k++) acc[m][k] = 0.f;

    for (int half = 0; half < 2; half++) {
        const float* src = half ? Hm : Ah;
        for (int i = tid; i < 64 * 150; i += 256) {
            int row = i / 150, col = i - row * 150;
            Xs[row][col] = src[(size_t)(r0 + row) * HHH + col];
        }
        __syncthreads();
        for (int d = 0; d < 150; d++) {
            float xv[4];
#pragma unroll
            for (int m = 0; m < 4; m++) xv[m] = Xs[rg + 16 * m][d];
            const int gd = half * 150 + d;
#pragma unroll
            for (int k = 0; k < 10; k++) {
                int h = c + 16 * k;
                int hc = h < HHH ? h : (HHH - 1);
                float w = Wt[(size_t)gd * HHH + hc];
#pragma unroll
                for (int m = 0; m < 4; m++) acc[m][k] = fmaf(xv[m], w, acc[m][k]);
            }
        }
        __syncthreads();
    }

#pragma unroll
    for (int k = 0; k < 10; k++) {
        int h = c + 16 * k;
        if (h >= HHH) continue;
        float bth = bt[h];
#pragma unroll
        for (int m = 0; m < 4; m++) {
            float v = acc[m][k] + bth;
            Out[(size_t)(r0 + rg + 16 * m) * HHH + h] = v > 0.f ? v : 0.f;
        }
    }
}

// ---------------------------------------------------------------------------
extern "C" void kernel_launch(void* const* d_in, const int* in_sizes, int n_in,
                              void* d_out, int out_size, void* d_ws, size_t ws_size,
                              hipStream_t stream)
{
    const float* Q  = (const float*)d_in[0];
    const float* A  = (const float*)d_in[1];
    const float* Wi = (const float*)d_in[2];
    const float* Wu = (const float*)d_in[3];
    const float* Wg = (const float*)d_in[4];
    const float* Wt = (const float*)d_in[5];
    const float* bi = (const float*)d_in[6];
    const float* bu = (const float*)d_in[7];
    const float* bg = (const float*)d_in[8];
    const float* bt = (const float*)d_in[9];
    float* out = (float*)d_out;

    char* ws = (char*)d_ws;
    float*  Qh  = (float*)(ws);                    // 9,830,400 B (later aliased as Hm)
    float*  Ahf = (float*)(ws + 9830400);          // 9,830,400 B
    __bf16* AhB = (__bf16*)(ws + 19660800);        // 5,505,024 B
    __bf16* QgB = (__bf16*)(ws + 25165824);        // 5,505,024 B
    __bf16* QhT = (__bf16*)(ws + 30670848);        // 5,898,240 B + 512 slack
    float*  Hm  = Qh;  // Qh fp32 dead after projg+transpose; reuse as Hm

    gate_kernel<<<NROWS / 64, 256, 0, stream>>>(Q, Wi, Wu, bi, bu, Qh, nullptr);
    gate_kernel<<<NROWS / 64, 256, 0, stream>>>(A, Wi, Wu, bi, bu, Ahf, AhB);
    projg_kernel<<<NROWS / 64, 256, 0, stream>>>(Qh, Wg, bg, QgB);
    transpose_qh<<<dim3(32, BB), 256, 0, stream>>>(Qh, QhT);
    attn_mfma<<<dim3(LA / 64, BB), 256, 0, stream>>>(QgB, AhB, QhT, Hm);
    final_kernel<<<NROWS / 64, 256, 0, stream>>>(Ahf, Hm, Wt, bt, out);
}

// Round 3
// 286.156 us; speedup vs baseline: 5.2376x; 1.6865x over previous
//
#include <hip/hip_runtime.h>
#include <math.h>

#define BB 8
#define LQ 2048
#define LA 2048
#define DD 300
#define HHH 150
#define NROWS (BB * LQ)

// padded bf16 layouts
#define KP 168          // row stride (elems) for QhB/AhB/QgB/HmB (336 B = 21*16)
#define QS 72           // q-stride for QhT tiles and PS (144 B = 9*16)
#define HP 160          // padded h rows in QhT tiles
#define XSS 328         // gate LDS X row stride (656 B = 41*16)

typedef __bf16 bf16x8 __attribute__((ext_vector_type(8)));
typedef __bf16 bf16x4 __attribute__((ext_vector_type(4)));
typedef float f32x4 __attribute__((ext_vector_type(4)));

__device__ __forceinline__ void gl_lds16(const void* g, void* l) {
    __builtin_amdgcn_global_load_lds(
        (const __attribute__((address_space(1))) void*)g,
        (__attribute__((address_space(3))) void*)l,
        16, 0, 0);
}

// ---------------------------------------------------------------------------
// Weight conversion: fp32 [D][H] -> bf16 transposed padded [Hp][Kp]
// z=0: WiT[160][320]  z=1: WuT[160][320]  z=2: WgT[160][160]
// z=3: Wt1[160][160] (rows 0..149 of Wt)  z=4: Wt2[160][160] (rows 150..299)
// ---------------------------------------------------------------------------
__global__ __launch_bounds__(256) void convert_weights(
    const float* __restrict__ Wi, const float* __restrict__ Wu,
    const float* __restrict__ Wg, const float* __restrict__ Wt,
    __bf16* __restrict__ WiT, __bf16* __restrict__ WuT,
    __bf16* __restrict__ WgT, __bf16* __restrict__ Wt1, __bf16* __restrict__ Wt2)
{
    const int z = blockIdx.y;
    const int i = blockIdx.x * 256 + threadIdx.x;
    if (z < 2) {
        if (i >= 160 * 320) return;
        int h = i / 320, d = i - h * 320;
        const float* src = z ? Wu : Wi;
        __bf16* dst = z ? WuT : WiT;
        float v = (h < HHH && d < DD) ? src[(size_t)d * HHH + h] : 0.f;
        dst[i] = (__bf16)v;
    } else {
        if (i >= 160 * 160) return;
        int h = i / 160, d = i - h * 160;
        const float* src = (z == 2) ? Wg : Wt;
        int doff = (z == 4) ? HHH : 0;
        float v = (h < HHH && d < HHH) ? src[(size_t)(d + doff) * HHH + h] : 0.f;
        __bf16* dst = (z == 2) ? WgT : ((z == 3) ? Wt1 : Wt2);
        dst[i] = (__bf16)v;
    }
}

// ---------------------------------------------------------------------------
// Gate (MFMA): Out = sigmoid(X@Wi+bi) * tanh(X@Wu+bu) -> bf16 [row][KP]
// Optional OutT: scatter into QhT tiles [tile=blockIdx.x][h][j] (j = row in tile)
// Block: 256 thr, 64 rows; wave w owns rows w*16..+15, all 150 h.
// ---------------------------------------------------------------------------
__global__ __launch_bounds__(256) void gate_mfma(
    const float* __restrict__ X,
    const __bf16* __restrict__ WiT, const __bf16* __restrict__ WuT,
    const float* __restrict__ bi, const float* __restrict__ bu,
    __bf16* __restrict__ OutBf, __bf16* __restrict__ OutT)
{
    __shared__ __align__(16) __bf16 Xs[64 * XSS];   // 41984 B
    const int tid = threadIdx.x;
    const int w = tid >> 6, lane = tid & 63;
    const int g = lane >> 4, n16 = lane & 15;
    const int r0 = blockIdx.x * 64;

    // stage + convert X rows (fp32 -> bf16); 300 = 4*75 so float4 never straddles
    const float4* src = (const float4*)(X + (size_t)r0 * DD);
    for (int i = tid; i < 4800; i += 256) {
        int row = i / 75, c4 = (i - row * 75) * 4;
        float4 v = src[i];
        bf16x4 pk = { (__bf16)v.x, (__bf16)v.y, (__bf16)v.z, (__bf16)v.w };
        *(bf16x4*)(Xs + row * XSS + c4) = pk;
    }
    // zero k-pad cols 300..327
    for (int i = tid; i < 64 * 7; i += 256) {
        int row = i / 7, c4 = 300 + (i - row * 7) * 4;
        *(bf16x4*)(Xs + row * XSS + c4) = (bf16x4){(__bf16)0.f,(__bf16)0.f,(__bf16)0.f,(__bf16)0.f};
    }
    __syncthreads();

    f32x4 ai[10], au[10];
#pragma unroll
    for (int t = 0; t < 10; t++) { ai[t] = (f32x4){0,0,0,0}; au[t] = (f32x4){0,0,0,0}; }

    for (int ks = 0; ks < 10; ks++) {
        bf16x8 af = *(const bf16x8*)(Xs + (w * 16 + n16) * XSS + ks * 32 + g * 8);
#pragma unroll
        for (int t = 0; t < 10; t++) {
            bf16x8 wi8 = *(const bf16x8*)(WiT + (size_t)(t * 16 + n16) * 320 + ks * 32 + g * 8);
            ai[t] = __builtin_amdgcn_mfma_f32_16x16x32_bf16(af, wi8, ai[t], 0, 0, 0);
            bf16x8 wu8 = *(const bf16x8*)(WuT + (size_t)(t * 16 + n16) * 320 + ks * 32 + g * 8);
            au[t] = __builtin_amdgcn_mfma_f32_16x16x32_bf16(af, wu8, au[t], 0, 0, 0);
        }
    }

#pragma unroll
    for (int t = 0; t < 10; t++) {
        int h = t * 16 + n16;
        int hc = h < HHH ? h : 0;
        float bih = bi[hc], buh = bu[hc];
#pragma unroll
        for (int r = 0; r < 4; r++) {
            int row = r0 + w * 16 + g * 4 + r;
            float v = 0.f;
            if (h < HHH) {
                float xi = ai[t][r] + bih, xu = au[t][r] + buh;
                v = (1.f / (1.f + __expf(-xi))) * tanhf(xu);
            }
            OutBf[(size_t)row * KP + h] = (__bf16)v;
            if (OutT) {
                int j = w * 16 + g * 4 + r;
                OutT[(size_t)blockIdx.x * (HP * QS) + h * QS + j] = (__bf16)v;
            }
        }
    }
}

// ---------------------------------------------------------------------------
// Qg = Qh @ Wg + bg  (MFMA, K=160) -> bf16 [row][KP]
// ---------------------------------------------------------------------------
__global__ __launch_bounds__(256) void projg_mfma(
    const __bf16* __restrict__ Xh, const __bf16* __restrict__ WgT,
    const float* __restrict__ bg, __bf16* __restrict__ OutBf)
{
    __shared__ __align__(16) __bf16 XS_[64 * KP];   // 21504 B
    const int tid = threadIdx.x;
    const int w = tid >> 6, lane = tid & 63;
    const int g = lane >> 4, n16 = lane & 15;
    const int r0 = blockIdx.x * 64;

    const char* slab = (const char*)(Xh + (size_t)r0 * KP);
    for (int ofs = w * 1024; ofs < 21504; ofs += 4096)
        gl_lds16(slab + ofs + lane * 16, (char*)XS_ + ofs);
    __syncthreads();

    f32x4 acc[10];
#pragma unroll
    for (int t = 0; t < 10; t++) acc[t] = (f32x4){0,0,0,0};

    for (int ks = 0; ks < 5; ks++) {
        bf16x8 af = *(const bf16x8*)(XS_ + (w * 16 + n16) * KP + ks * 32 + g * 8);
#pragma unroll
        for (int t = 0; t < 10; t++) {
            bf16x8 b8 = *(const bf16x8*)(WgT + (size_t)(t * 16 + n16) * 160 + ks * 32 + g * 8);
            acc[t] = __builtin_amdgcn_mfma_f32_16x16x32_bf16(af, b8, acc[t], 0, 0, 0);
        }
    }

#pragma unroll
    for (int t = 0; t < 10; t++) {
        int h = t * 16 + n16;
        int hc = h < HHH ? h : 0;
        float bgh = bg[hc];
#pragma unroll
        for (int r = 0; r < 4; r++) {
            int row = r0 + w * 16 + g * 4 + r;
            float v = (h < HHH) ? (acc[t][r] + bgh) : 0.f;
            OutBf[(size_t)row * KP + h] = (__bf16)v;
        }
    }
}

// ---------------------------------------------------------------------------
// MFMA flash attention (no-max softmax; |S| small so exp is safe in fp32)
// block = (a-tile of 64, batch); wave w owns a-rows w*16..w*16+15
// ---------------------------------------------------------------------------
__global__ __launch_bounds__(256, 1) void attn_mfma(
    const __bf16* __restrict__ QgG, const __bf16* __restrict__ AhG,
    const __bf16* __restrict__ QhTG, __bf16* __restrict__ HmB)
{
    __shared__ __align__(16) __bf16 AhS[64 * KP];      // 21504 B
    __shared__ __align__(16) __bf16 QgS[64 * KP];      // 21504 B
    __shared__ __align__(16) __bf16 QhTS[23552 / 2];   // 160x72 (+tail slack)
    __shared__ __align__(16) __bf16 PS[64 * QS];       // 9216 B

    const int tid = threadIdx.x;
    const int w = tid >> 6;
    const int lane = tid & 63;
    const int g = lane >> 4;
    const int n16 = lane & 15;
    const int b = blockIdx.y;
    const int a0 = blockIdx.x * 64;

    const char* ahSlab = (const char*)(AhG + ((size_t)b * LA + a0) * KP);
    for (int ofs = w * 1024; ofs < 21504; ofs += 4096)
        gl_lds16(ahSlab + ofs + lane * 16, (char*)AhS + ofs);

    float lsum[4] = {0.f, 0.f, 0.f, 0.f};
    f32x4 acc[10];
#pragma unroll
    for (int t = 0; t < 10; t++) acc[t] = (f32x4){0.f, 0.f, 0.f, 0.f};

    const char* qgBase = (const char*)(QgG + (size_t)b * LQ * KP);
    const char* qhBase = (const char*)(QhTG + (size_t)b * 32 * HP * QS);

    for (int qt = 0; qt < 32; qt++) {
        __syncthreads();
        const char* qgSlab = qgBase + (size_t)qt * 64 * (KP * 2);
        for (int ofs = w * 1024; ofs < 21504; ofs += 4096)
            gl_lds16(qgSlab + ofs + lane * 16, (char*)QgS + ofs);
        const char* qhSlab = qhBase + (size_t)qt * (HP * QS * 2);
        for (int ofs = w * 1024; ofs < 23552; ofs += 4096)
            gl_lds16(qhSlab + ofs + lane * 16, (char*)QhTS + ofs);
        __syncthreads();

        // ---- S = Ah(16a) x Qg(64q), K=160 ----
        bf16x8 af[5];
#pragma unroll
        for (int ks = 0; ks < 5; ks++)
            af[ks] = *(const bf16x8*)(AhS + (w * 16 + n16) * KP + ks * 32 + g * 8);
        f32x4 s[4];
#pragma unroll
        for (int t = 0; t < 4; t++) s[t] = (f32x4){0.f, 0.f, 0.f, 0.f};
#pragma unroll
        for (int t = 0; t < 4; t++)
#pragma unroll
            for (int ks = 0; ks < 5; ks++) {
                bf16x8 bf_ = *(const bf16x8*)(QgS + (t * 16 + n16) * KP + ks * 32 + g * 8);
                s[t] = __builtin_amdgcn_mfma_f32_16x16x32_bf16(af[ks], bf_, s[t], 0, 0, 0);
            }

        // ---- P = exp(S); accumulate l; P -> LDS (bf16) ----
#pragma unroll
        for (int t = 0; t < 4; t++)
#pragma unroll
            for (int r = 0; r < 4; r++) {
                float p = __expf(s[t][r]);
                lsum[r] += p;
                PS[(w * 16 + g * 4 + r) * QS + t * 16 + n16] = (__bf16)p;
            }

        // ---- O += P(16a x 64q) x QhT(64q x 160h) ----
#pragma unroll
        for (int ks = 0; ks < 2; ks++) {
            bf16x8 pf = *(const bf16x8*)(PS + (w * 16 + n16) * QS + ks * 32 + g * 8);
#pragma unroll
            for (int t = 0; t < 10; t++) {
                bf16x8 vf = *(const bf16x8*)(QhTS + (t * 16 + n16) * QS + ks * 32 + g * 8);
                acc[t] = __builtin_amdgcn_mfma_f32_16x16x32_bf16(pf, vf, acc[t], 0, 0, 0);
            }
        }
    }

    // ---- normalize and store (bf16, padded) ----
    float invl[4];
#pragma unroll
    for (int r = 0; r < 4; r++) {
        float sres = lsum[r];
#pragma unroll
        for (int m = 1; m < 16; m <<= 1) sres += __shfl_xor(sres, m, 64);
        invl[r] = 1.f / sres;
    }
#pragma unroll
    for (int t = 0; t < 10; t++) {
        int h = t * 16 + n16;
#pragma unroll
        for (int r = 0; r < 4; r++) {
            int row = a0 + w * 16 + g * 4 + r;
            float v = (h < HHH) ? acc[t][r] * invl[r] : 0.f;
            HmB[((size_t)b * LA + row) * KP + h] = (__bf16)v;
        }
    }
}

// ---------------------------------------------------------------------------
// Final (MFMA): Out = relu([Ah, Hm] @ Wt + bt) -> fp32
// ---------------------------------------------------------------------------
__global__ __launch_bounds__(256) void final_mfma(
    const __bf16* __restrict__ AhB, const __bf16* __restrict__ HmG,
    const __bf16* __restrict__ Wt1, const __bf16* __restrict__ Wt2,
    const float* __restrict__ bt, float* __restrict__ Out)
{
    __shared__ __align__(16) __bf16 AS[64 * KP];
    __shared__ __align__(16) __bf16 HS[64 * KP];
    const int tid = threadIdx.x;
    const int w = tid >> 6, lane = tid & 63;
    const int g = lane >> 4, n16 = lane & 15;
    const int r0 = blockIdx.x * 64;

    const char* aSlab = (const char*)(AhB + (size_t)r0 * KP);
    const char* hSlab = (const char*)(HmG + (size_t)r0 * KP);
    for (int ofs = w * 1024; ofs < 21504; ofs += 4096) {
        gl_lds16(aSlab + ofs + lane * 16, (char*)AS + ofs);
        gl_lds16(hSlab + ofs + lane * 16, (char*)HS + ofs);
    }
    __syncthreads();

    f32x4 acc[10];
#pragma unroll
    for (int t = 0; t < 10; t++) acc[t] = (f32x4){0,0,0,0};

    for (int ks = 0; ks < 5; ks++) {
        bf16x8 af = *(const bf16x8*)(AS + (w * 16 + n16) * KP + ks * 32 + g * 8);
#pragma unroll
        for (int t = 0; t < 10; t++) {
            bf16x8 b8 = *(const bf16x8*)(Wt1 + (size_t)(t * 16 + n16) * 160 + ks * 32 + g * 8);
            acc[t] = __builtin_amdgcn_mfma_f32_16x16x32_bf16(af, b8, acc[t], 0, 0, 0);
        }
    }
    for (int ks = 0; ks < 5; ks++) {
        bf16x8 af = *(const bf16x8*)(HS + (w * 16 + n16) * KP + ks * 32 + g * 8);
#pragma unroll
        for (int t = 0; t < 10; t++) {
            bf16x8 b8 = *(const bf16x8*)(Wt2 + (size_t)(t * 16 + n16) * 160 + ks * 32 + g * 8);
            acc[t] = __builtin_amdgcn_mfma_f32_16x16x32_bf16(af, b8, acc[t], 0, 0, 0);
        }
    }

#pragma unroll
    for (int t = 0; t < 10; t++) {
        int h = t * 16 + n16;
        if (h >= HHH) continue;
        float bth = bt[h];
#pragma unroll
        for (int r = 0; r < 4; r++) {
            int row = r0 + w * 16 + g * 4 + r;
            float v = acc[t][r] + bth;
            Out[(size_t)row * HHH + h] = v > 0.f ? v : 0.f;
        }
    }
}

// ---------------------------------------------------------------------------
extern "C" void kernel_launch(void* const* d_in, const int* in_sizes, int n_in,
                              void* d_out, int out_size, void* d_ws, size_t ws_size,
                              hipStream_t stream)
{
    const float* Q  = (const float*)d_in[0];
    const float* A  = (const float*)d_in[1];
    const float* Wi = (const float*)d_in[2];
    const float* Wu = (const float*)d_in[3];
    const float* Wg = (const float*)d_in[4];
    const float* Wt = (const float*)d_in[5];
    const float* bi = (const float*)d_in[6];
    const float* bu = (const float*)d_in[7];
    const float* bg = (const float*)d_in[8];
    const float* bt = (const float*)d_in[9];
    float* out = (float*)d_out;

    char* ws = (char*)d_ws;
    __bf16* QhB = (__bf16*)(ws);                    // 5,505,024 B
    __bf16* AhB = (__bf16*)(ws + 5505024);          // 5,505,024 B
    __bf16* QgB = (__bf16*)(ws + 11010048);         // 5,505,024 B
    __bf16* QhT = (__bf16*)(ws + 16515072);         // 5,898,240 B (+512 stage slack)
    __bf16* HmB = (__bf16*)(ws + 22414336);         // 5,505,024 B
    __bf16* WiT = (__bf16*)(ws + 27919360);         // 102,400 B
    __bf16* WuT = (__bf16*)(ws + 28021760);         // 102,400 B
    __bf16* WgT = (__bf16*)(ws + 28124160);         //  51,200 B
    __bf16* Wt1 = (__bf16*)(ws + 28175360);         //  51,200 B
    __bf16* Wt2 = (__bf16*)(ws + 28226560);         //  51,200 B

    convert_weights<<<dim3(200, 5), 256, 0, stream>>>(Wi, Wu, Wg, Wt,
                                                      WiT, WuT, WgT, Wt1, Wt2);
    gate_mfma<<<NROWS / 64, 256, 0, stream>>>(Q, WiT, WuT, bi, bu, QhB, QhT);
    gate_mfma<<<NROWS / 64, 256, 0, stream>>>(A, WiT, WuT, bi, bu, AhB, nullptr);
    projg_mfma<<<NROWS / 64, 256, 0, stream>>>(QhB, WgT, bg, QgB);
    attn_mfma<<<dim3(LA / 64, BB), 256, 0, stream>>>(QgB, AhB, QhT, HmB);
    final_mfma<<<NROWS / 64, 256, 0, stream>>>(AhB, HmB, Wt1, Wt2, bt, out);
}

// Round 4
// 228.775 us; speedup vs baseline: 6.5513x; 1.2508x over previous
//
#include <hip/hip_runtime.h>
#include <math.h>

#define BB 8
#define LQ 2048
#define LA 2048
#define DD 300
#define HHH 150
#define NROWS (BB * LQ)

#define KP 168          // row stride (elems) for QhB/AhB/Qg/HmB rows (336 B)
#define QTS 72          // QhT q-stride (144 B; 36 words % 32 = 4 -> conflict-free b128)
#define PSS 76          // PS stride (38 words % 32 = 6 -> conflict-free)
#define HP 160          // padded h rows in QhT tiles
#define XSS 328         // gate LDS X row stride (656 B; 164 words % 32 = 4 -> cf)
#define WKS 328         // Wi/Wu transposed row stride (k=320 padded to 328)
#define WKS2 168        // Wg/Wt1/Wt2 transposed row stride
#define SLAB_B 45056    // bytes per (b,qt) staging slab: [Qg 64x168 | pad | QhT 160x72]
#define SLAB_E 22528    // elems per slab
#define QHT_OFF_E 11008 // elem offset of QhT within slab (22016 B)

typedef __bf16 bf16x8 __attribute__((ext_vector_type(8)));
typedef __bf16 bf16x4 __attribute__((ext_vector_type(4)));
typedef float f32x4 __attribute__((ext_vector_type(4)));

__device__ __forceinline__ void gl_lds16(const void* g, void* l) {
    __builtin_amdgcn_global_load_lds(
        (const __attribute__((address_space(1))) void*)g,
        (__attribute__((address_space(3))) void*)l,
        16, 0, 0);
}

// ---------------------------------------------------------------------------
// Weight conversion -> transposed, padded bf16.
// z=0: WiT[160][328]  z=1: WuT[160][328]
// z=2: WgT[160][168]  z=3: Wt1[160][168]  z=4: Wt2[160][168]
// ---------------------------------------------------------------------------
__global__ __launch_bounds__(256) void convert_weights(
    const float* __restrict__ Wi, const float* __restrict__ Wu,
    const float* __restrict__ Wg, const float* __restrict__ Wt,
    __bf16* __restrict__ WiT, __bf16* __restrict__ WuT,
    __bf16* __restrict__ WgT, __bf16* __restrict__ Wt1, __bf16* __restrict__ Wt2)
{
    const int z = blockIdx.y;
    const int i = blockIdx.x * 256 + threadIdx.x;
    if (z < 2) {
        if (i >= 160 * WKS) return;
        int h = i / WKS, d = i - h * WKS;
        const float* src = z ? Wu : Wi;
        __bf16* dst = z ? WuT : WiT;
        float v = (h < HHH && d < DD) ? src[(size_t)d * HHH + h] : 0.f;
        dst[i] = (__bf16)v;
    } else {
        if (i >= 160 * WKS2) return;
        int h = i / WKS2, d = i - h * WKS2;
        const float* src = (z == 2) ? Wg : Wt;
        int doff = (z == 4) ? HHH : 0;
        float v = (h < HHH && d < HHH) ? src[(size_t)(d + doff) * HHH + h] : 0.f;
        __bf16* dst = (z == 2) ? WgT : ((z == 3) ? Wt1 : Wt2);
        dst[i] = (__bf16)v;
    }
}

// ---------------------------------------------------------------------------
// Gate (MFMA, LDS-staged weights, two phases): Out = sigmoid(X@Wi+bi)*tanh(X@Wu+bu)
// OutBf: [row][168] bf16. OutT (optional): QhT part of slab [tile][160][72].
// ---------------------------------------------------------------------------
__global__ __launch_bounds__(256, 1) void gate_mfma(
    const float* __restrict__ X,
    const __bf16* __restrict__ WiT, const __bf16* __restrict__ WuT,
    const float* __restrict__ bi, const float* __restrict__ bu,
    __bf16* __restrict__ OutBf, __bf16* __restrict__ SlabT)
{
    __shared__ __align__(16) __bf16 Xs[64 * XSS];    // 41984 B
    __shared__ __align__(16) __bf16 WS[160 * WKS];   // 104960 B
    const int tid = threadIdx.x;
    const int w = tid >> 6, lane = tid & 63;
    const int g = lane >> 4, n16 = lane & 15;
    const int r0 = blockIdx.x * 64;

    // stage + convert X (fp32 -> bf16); 300 = 75 float4 per row
    const float4* src = (const float4*)(X + (size_t)r0 * DD);
    for (int i = tid; i < 4800; i += 256) {
        int row = i / 75, c4 = (i - row * 75) * 4;
        float4 v = src[i];
        *(bf16x4*)(Xs + row * XSS + c4) =
            (bf16x4){ (__bf16)v.x, (__bf16)v.y, (__bf16)v.z, (__bf16)v.w };
    }
    for (int i = tid; i < 64 * 7; i += 256) {
        int row = i / 7, c4 = 300 + (i - row * 7) * 4;
        *(bf16x4*)(Xs + row * XSS + c4) = (bf16x4){(__bf16)0.f,(__bf16)0.f,(__bf16)0.f,(__bf16)0.f};
    }
    // stage Wi into WS (flat 16B copies; 160*328*2/16 = 6560 chunks)
    {
        const bf16x8* wsrc = (const bf16x8*)WiT;
        for (int i = tid; i < 6560; i += 256) *(bf16x8*)(WS + i * 8) = wsrc[i];
    }
    __syncthreads();

    bf16x8 af[10];
#pragma unroll
    for (int ks = 0; ks < 10; ks++)
        af[ks] = *(const bf16x8*)(Xs + (w * 16 + n16) * XSS + ks * 32 + g * 8);

    f32x4 ai[10];
#pragma unroll
    for (int t = 0; t < 10; t++) ai[t] = (f32x4){0,0,0,0};
    for (int ks = 0; ks < 10; ks++)
#pragma unroll
        for (int t = 0; t < 10; t++) {
            bf16x8 b8 = *(const bf16x8*)(WS + (t * 16 + n16) * WKS + ks * 32 + g * 8);
            ai[t] = __builtin_amdgcn_mfma_f32_16x16x32_bf16(af[ks], b8, ai[t], 0, 0, 0);
        }
    __syncthreads();
    // stage Wu over WS
    {
        const bf16x8* wsrc = (const bf16x8*)WuT;
        for (int i = tid; i < 6560; i += 256) *(bf16x8*)(WS + i * 8) = wsrc[i];
    }
    __syncthreads();

    f32x4 au[10];
#pragma unroll
    for (int t = 0; t < 10; t++) au[t] = (f32x4){0,0,0,0};
    for (int ks = 0; ks < 10; ks++)
#pragma unroll
        for (int t = 0; t < 10; t++) {
            bf16x8 b8 = *(const bf16x8*)(WS + (t * 16 + n16) * WKS + ks * 32 + g * 8);
            au[t] = __builtin_amdgcn_mfma_f32_16x16x32_bf16(af[ks], b8, au[t], 0, 0, 0);
        }

#pragma unroll
    for (int t = 0; t < 10; t++) {
        int h = t * 16 + n16;
        int hc = h < HHH ? h : 0;
        float bih = bi[hc], buh = bu[hc];
#pragma unroll
        for (int r = 0; r < 4; r++) {
            int j = w * 16 + g * 4 + r;
            int row = r0 + j;
            float v = 0.f;
            if (h < HHH) {
                float xi = ai[t][r] + bih, xu = au[t][r] + buh;
                v = (1.f / (1.f + __expf(-xi))) * tanhf(xu);
            }
            OutBf[(size_t)row * KP + h] = (__bf16)v;
            if (SlabT)
                SlabT[(size_t)blockIdx.x * SLAB_E + QHT_OFF_E + h * QTS + j] = (__bf16)v;
        }
    }
}

// ---------------------------------------------------------------------------
// Qg = Qh @ Wg + bg  (MFMA, K=160, LDS weights) -> Qg part of slab
// ---------------------------------------------------------------------------
__global__ __launch_bounds__(256, 1) void projg_mfma(
    const __bf16* __restrict__ Xh, const __bf16* __restrict__ WgT,
    const float* __restrict__ bg, __bf16* __restrict__ Slab)
{
    __shared__ __align__(16) __bf16 XS_[64 * KP];     // 21504 B
    __shared__ __align__(16) __bf16 WgS[160 * WKS2];  // 53760 B
    const int tid = threadIdx.x;
    const int w = tid >> 6, lane = tid & 63;
    const int g = lane >> 4, n16 = lane & 15;
    const int r0 = blockIdx.x * 64;

    const char* slab = (const char*)(Xh + (size_t)r0 * KP);
    for (int ofs = w * 1024; ofs < 21504; ofs += 4096)
        gl_lds16(slab + ofs + lane * 16, (char*)XS_ + ofs);
    {
        const bf16x8* wsrc = (const bf16x8*)WgT;
        for (int i = tid; i < 3360; i += 256) *(bf16x8*)(WgS + i * 8) = wsrc[i];
    }
    __syncthreads();

    bf16x8 af[5];
#pragma unroll
    for (int ks = 0; ks < 5; ks++)
        af[ks] = *(const bf16x8*)(XS_ + (w * 16 + n16) * KP + ks * 32 + g * 8);

    f32x4 acc[10];
#pragma unroll
    for (int t = 0; t < 10; t++) acc[t] = (f32x4){0,0,0,0};
    for (int ks = 0; ks < 5; ks++)
#pragma unroll
        for (int t = 0; t < 10; t++) {
            bf16x8 b8 = *(const bf16x8*)(WgS + (t * 16 + n16) * WKS2 + ks * 32 + g * 8);
            acc[t] = __builtin_amdgcn_mfma_f32_16x16x32_bf16(af[ks], b8, acc[t], 0, 0, 0);
        }

#pragma unroll
    for (int t = 0; t < 10; t++) {
        int h = t * 16 + n16;
        int hc = h < HHH ? h : 0;
        float bgh = bg[hc];
#pragma unroll
        for (int r = 0; r < 4; r++) {
            int j = w * 16 + g * 4 + r;
            float v = (h < HHH) ? (acc[t][r] + bgh) : 0.f;
            Slab[(size_t)blockIdx.x * SLAB_E + j * KP + h] = (__bf16)v;
        }
    }
}

// ---------------------------------------------------------------------------
// MFMA flash attention, double-buffered slab staging.
// block = (64 a-rows, batch); wave w owns a-rows w*16..+15.
// ---------------------------------------------------------------------------
__global__ __launch_bounds__(256, 1) void attn_mfma(
    const __bf16* __restrict__ SlabG, const __bf16* __restrict__ AhG,
    __bf16* __restrict__ HmB)
{
    __shared__ __align__(16) __bf16 AhS[64 * KP];     // 21504 B
    __shared__ __align__(16) __bf16 Buf[2][SLAB_E];   // 2 x 45056 B
    __shared__ __align__(16) __bf16 PS[64 * PSS];     // 9728 B

    const int tid = threadIdx.x;
    const int w = tid >> 6;
    const int lane = tid & 63;
    const int g = lane >> 4;
    const int n16 = lane & 15;
    const int b = blockIdx.y;
    const int a0 = blockIdx.x * 64;

    // prologue staging: Ah tile + slab(qt=0)
    const char* ahSlab = (const char*)(AhG + ((size_t)b * LA + a0) * KP);
    for (int ofs = w * 1024; ofs < 21504; ofs += 4096)
        gl_lds16(ahSlab + ofs + lane * 16, (char*)AhS + ofs);
    const char* slabBase = (const char*)SlabG + (size_t)b * 32 * SLAB_B;
    for (int ofs = w * 1024; ofs < SLAB_B; ofs += 4096)
        gl_lds16(slabBase + ofs + lane * 16, (char*)Buf[0] + ofs);
    __syncthreads();

    bf16x8 af[5];
#pragma unroll
    for (int ks = 0; ks < 5; ks++)
        af[ks] = *(const bf16x8*)(AhS + (w * 16 + n16) * KP + ks * 32 + g * 8);

    float lsum[4] = {0.f, 0.f, 0.f, 0.f};
    f32x4 acc[10];
#pragma unroll
    for (int t = 0; t < 10; t++) acc[t] = (f32x4){0.f, 0.f, 0.f, 0.f};

    for (int qt = 0; qt < 32; qt++) {
        const int cur = qt & 1;
        // issue next tile's staging (overlaps with this tile's compute)
        if (qt < 31) {
            const char* nslab = slabBase + (size_t)(qt + 1) * SLAB_B;
            for (int ofs = w * 1024; ofs < SLAB_B; ofs += 4096)
                gl_lds16(nslab + ofs + lane * 16, (char*)Buf[cur ^ 1] + ofs);
        }
        const __bf16* Bq = Buf[cur];
        const __bf16* Bv = Buf[cur] + QHT_OFF_E;

        // ---- S = Ah(16a) x Qg(64q), K=160 ----
        f32x4 s[4];
#pragma unroll
        for (int t = 0; t < 4; t++) s[t] = (f32x4){0.f, 0.f, 0.f, 0.f};
#pragma unroll
        for (int t = 0; t < 4; t++)
#pragma unroll
            for (int ks = 0; ks < 5; ks++) {
                bf16x8 bf_ = *(const bf16x8*)(Bq + (t * 16 + n16) * KP + ks * 32 + g * 8);
                s[t] = __builtin_amdgcn_mfma_f32_16x16x32_bf16(af[ks], bf_, s[t], 0, 0, 0);
            }

        // ---- P = exp(S); accumulate l; P -> LDS (bf16, wave-private rows) ----
#pragma unroll
        for (int t = 0; t < 4; t++)
#pragma unroll
            for (int r = 0; r < 4; r++) {
                float p = __expf(s[t][r]);
                lsum[r] += p;
                PS[(w * 16 + g * 4 + r) * PSS + t * 16 + n16] = (__bf16)p;
            }

        // ---- O += P(16a x 64q) x QhT(64q x 160h) ----
#pragma unroll
        for (int ks = 0; ks < 2; ks++) {
            bf16x8 pf = *(const bf16x8*)(PS + (w * 16 + n16) * PSS + ks * 32 + g * 8);
#pragma unroll
            for (int t = 0; t < 10; t++) {
                bf16x8 vf = *(const bf16x8*)(Bv + (t * 16 + n16) * QTS + ks * 32 + g * 8);
                acc[t] = __builtin_amdgcn_mfma_f32_16x16x32_bf16(pf, vf, acc[t], 0, 0, 0);
            }
        }
        __syncthreads();  // drains next-tile staging; separates Buf reuse
    }

    // ---- normalize and store (bf16, padded rows of 168) ----
    float invl[4];
#pragma unroll
    for (int r = 0; r < 4; r++) {
        float sres = lsum[r];
#pragma unroll
        for (int m = 1; m < 16; m <<= 1) sres += __shfl_xor(sres, m, 64);
        invl[r] = 1.f / sres;
    }
#pragma unroll
    for (int t = 0; t < 10; t++) {
        int h = t * 16 + n16;
#pragma unroll
        for (int r = 0; r < 4; r++) {
            int row = a0 + w * 16 + g * 4 + r;
            float v = (h < HHH) ? acc[t][r] * invl[r] : 0.f;
            HmB[((size_t)b * LA + row) * KP + h] = (__bf16)v;
        }
    }
}

// ---------------------------------------------------------------------------
// Final (MFMA, LDS weights): Out = relu([Ah, Hm] @ Wt + bt) -> fp32
// ---------------------------------------------------------------------------
__global__ __launch_bounds__(256, 1) void final_mfma(
    const __bf16* __restrict__ AhB, const __bf16* __restrict__ HmG,
    const __bf16* __restrict__ Wt12,   // Wt1 then Wt2, contiguous
    const float* __restrict__ bt, float* __restrict__ Out)
{
    __shared__ __align__(16) __bf16 AS[64 * KP];          // 21504 B
    __shared__ __align__(16) __bf16 HS[64 * KP];          // 21504 B
    __shared__ __align__(16) __bf16 WtS[2 * 160 * WKS2];  // 107520 B
    const int tid = threadIdx.x;
    const int w = tid >> 6, lane = tid & 63;
    const int g = lane >> 4, n16 = lane & 15;
    const int r0 = blockIdx.x * 64;

    const char* aSlab = (const char*)(AhB + (size_t)r0 * KP);
    const char* hSlab = (const char*)(HmG + (size_t)r0 * KP);
    for (int ofs = w * 1024; ofs < 21504; ofs += 4096) {
        gl_lds16(aSlab + ofs + lane * 16, (char*)AS + ofs);
        gl_lds16(hSlab + ofs + lane * 16, (char*)HS + ofs);
    }
    {
        const bf16x8* wsrc = (const bf16x8*)Wt12;
        for (int i = tid; i < 6720; i += 256) *(bf16x8*)(WtS + i * 8) = wsrc[i];
    }
    __syncthreads();

    bf16x8 afA[5], afH[5];
#pragma unroll
    for (int ks = 0; ks < 5; ks++) {
        afA[ks] = *(const bf16x8*)(AS + (w * 16 + n16) * KP + ks * 32 + g * 8);
        afH[ks] = *(const bf16x8*)(HS + (w * 16 + n16) * KP + ks * 32 + g * 8);
    }

    f32x4 acc[10];
#pragma unroll
    for (int t = 0; t < 10; t++) acc[t] = (f32x4){0,0,0,0};
    for (int ks = 0; ks < 5; ks++)
#pragma unroll
        for (int t = 0; t < 10; t++) {
            bf16x8 b8 = *(const bf16x8*)(WtS + (t * 16 + n16) * WKS2 + ks * 32 + g * 8);
            acc[t] = __builtin_amdgcn_mfma_f32_16x16x32_bf16(afA[ks], b8, acc[t], 0, 0, 0);
        }
    for (int ks = 0; ks < 5; ks++)
#pragma unroll
        for (int t = 0; t < 10; t++) {
            bf16x8 b8 = *(const bf16x8*)(WtS + (160 + t * 16 + n16) * WKS2 + ks * 32 + g * 8);
            acc[t] = __builtin_amdgcn_mfma_f32_16x16x32_bf16(afH[ks], b8, acc[t], 0, 0, 0);
        }

#pragma unroll
    for (int t = 0; t < 10; t++) {
        int h = t * 16 + n16;
        if (h >= HHH) continue;
        float bth = bt[h];
#pragma unroll
        for (int r = 0; r < 4; r++) {
            int row = r0 + w * 16 + g * 4 + r;
            float v = acc[t][r] + bth;
            Out[(size_t)row * HHH + h] = v > 0.f ? v : 0.f;
        }
    }
}

// ---------------------------------------------------------------------------
extern "C" void kernel_launch(void* const* d_in, const int* in_sizes, int n_in,
                              void* d_out, int out_size, void* d_ws, size_t ws_size,
                              hipStream_t stream)
{
    const float* Q  = (const float*)d_in[0];
    const float* A  = (const float*)d_in[1];
    const float* Wi = (const float*)d_in[2];
    const float* Wu = (const float*)d_in[3];
    const float* Wg = (const float*)d_in[4];
    const float* Wt = (const float*)d_in[5];
    const float* bi = (const float*)d_in[6];
    const float* bu = (const float*)d_in[7];
    const float* bg = (const float*)d_in[8];
    const float* bt = (const float*)d_in[9];
    float* out = (float*)d_out;

    char* ws = (char*)d_ws;
    __bf16* QhB  = (__bf16*)(ws);                    // 5,505,024 B
    __bf16* AhB  = (__bf16*)(ws + 5505024);          // 5,505,024 B
    __bf16* HmB  = (__bf16*)(ws + 11010048);         // 5,505,024 B
    __bf16* Slab = (__bf16*)(ws + 16515072);         // 11,534,336 B (256 slabs)
    __bf16* WiT  = (__bf16*)(ws + 28049408);         // 104,960 B
    __bf16* WuT  = (__bf16*)(ws + 28154368);         // 104,960 B
    __bf16* WgT  = (__bf16*)(ws + 28259328);         // 53,760 B
    __bf16* Wt12 = (__bf16*)(ws + 28313088);         // 107,520 B (Wt1|Wt2)
    __bf16* Wt1  = Wt12;
    __bf16* Wt2  = Wt12 + 160 * WKS2;

    convert_weights<<<dim3(205, 5), 256, 0, stream>>>(Wi, Wu, Wg, Wt,
                                                      WiT, WuT, WgT, Wt1, Wt2);
    gate_mfma<<<NROWS / 64, 256, 0, stream>>>(Q, WiT, WuT, bi, bu, QhB, Slab);
    gate_mfma<<<NROWS / 64, 256, 0, stream>>>(A, WiT, WuT, bi, bu, AhB, nullptr);
    projg_mfma<<<NROWS / 64, 256, 0, stream>>>(QhB, WgT, bg, Slab);
    attn_mfma<<<dim3(LA / 64, BB), 256, 0, stream>>>(Slab, AhB, HmB);
    final_mfma<<<NROWS / 64, 256, 0, stream>>>(AhB, HmB, Wt12, bt, out);
}

// Round 5
// 188.473 us; speedup vs baseline: 7.9522x; 1.2138x over previous
//
#include <hip/hip_runtime.h>
#include <math.h>

#define BB 8
#define LQ 2048
#define DD 300
#define HHH 150
#define NROWS (BB * LQ)

#define KP 168          // row stride (elems) for AhB / Qg / W rows (336 B)
#define QTS 72          // QhT q-stride and PS stride (144 B)
#define XSS 328         // gate X LDS row stride (656 B)
#define WCE 27136       // padded elems per W chunk (54272 B, 53 KiB staging unit)
#define JT 144          // QhT build-buffer j stride
#define SLAB_B 45056    // per-(b,qt) slab: [Qg 64x168 | pad 512B | QhT 160x72]
#define SLAB_E 22528
#define QHT_OFF_E 11008

typedef __bf16 bf16x8 __attribute__((ext_vector_type(8)));
typedef __bf16 bf16x4 __attribute__((ext_vector_type(4)));
typedef float f32x16 __attribute__((ext_vector_type(16)));

__device__ __forceinline__ void gl_lds16(const void* g, void* l) {
    __builtin_amdgcn_global_load_lds(
        (const __attribute__((address_space(1))) void*)g,
        (__attribute__((address_space(3))) void*)l,
        16, 0, 0);
}
// flat async global->LDS copy; bytes must be a multiple of 1024
__device__ __forceinline__ void stage_flat(const void* g, void* l, int bytes,
                                           int w, int lane) {
    for (int ofs = w * 1024; ofs < bytes; ofs += 4096)
        gl_lds16((const char*)g + ofs + lane * 16, (char*)l + ofs);
}
__device__ __forceinline__ f32x16 z16() {
    f32x16 v;
#pragma unroll
    for (int i = 0; i < 16; i++) v[i] = 0.f;
    return v;
}

// ---------------------------------------------------------------------------
// Weight conversion. z=0/1: WiC/WuC [2 chunks][160h][168k] (chunk c = k 160c..),
// padded to WCE elems/chunk. z=2: WgT [160][168]+pad. z=3: Wt12 [2][160][168].
// ---------------------------------------------------------------------------
__global__ __launch_bounds__(256) void convert_weights(
    const float* __restrict__ Wi, const float* __restrict__ Wu,
    const float* __restrict__ Wg, const float* __restrict__ Wt,
    __bf16* __restrict__ WiC, __bf16* __restrict__ WuC,
    __bf16* __restrict__ WgT, __bf16* __restrict__ Wt12)
{
    const int z = blockIdx.y;
    const int i = blockIdx.x * 256 + threadIdx.x;
    if (z < 2) {
        if (i >= 2 * WCE) return;
        int c = i / WCE, rem = i - c * WCE;
        float v = 0.f;
        if (rem < 160 * KP) {
            int h = rem / KP, kc = rem - h * KP;
            int d = c * 160 + kc;
            if (kc < 160 && d < DD && h < HHH) v = (z ? Wu : Wi)[(size_t)d * HHH + h];
        }
        (z ? WuC : WiC)[i] = (__bf16)v;
    } else if (z == 2) {
        if (i >= WCE) return;
        float v = 0.f;
        if (i < 160 * KP) {
            int h = i / KP, kc = i - h * KP;
            if (kc < HHH && h < HHH) v = Wg[(size_t)kc * HHH + h];
        }
        WgT[i] = (__bf16)v;
    } else {
        if (i >= 2 * 160 * KP) return;
        int c = i / (160 * KP), rem = i - c * (160 * KP);
        int h = rem / KP, kc = rem - h * KP;
        float v = (kc < HHH && h < HHH) ? Wt[(size_t)(c * HHH + kc) * HHH + h] : 0.f;
        Wt12[i] = (__bf16)v;
    }
}

// ---------------------------------------------------------------------------
// gatep: z=1: Ah = gate(A) -> AhB [row][168].
//        z=0: Qh = gate(Q) (kept on-chip) -> Qg = Qh@Wg+bg -> slab Qg,
//             and QhT (transposed Qh) -> slab QhT.
// Block = 128 rows, 4 waves x 32-row m-tile, mfma 32x32x16.
// ---------------------------------------------------------------------------
__global__ __launch_bounds__(256, 1) void gatep(
    const float* __restrict__ Q, const float* __restrict__ A,
    const __bf16* __restrict__ WiC, const __bf16* __restrict__ WuC,
    const __bf16* __restrict__ WgT,
    const float* __restrict__ bi, const float* __restrict__ bu,
    const float* __restrict__ bg,
    __bf16* __restrict__ AhB, __bf16* __restrict__ Slab)
{
    __shared__ __align__(16) __bf16 Xs[128 * XSS];  // 83968 B (later: QhA [128][168])
    __shared__ __align__(16) __bf16 WS[WCE];        // 54272 B (also QhTbuf [160][144])
    const int tid = threadIdx.x;
    const int w = tid >> 6, lane = tid & 63;
    const int m32 = lane & 31, half = lane >> 5;
    const int z = blockIdx.y;
    const int r0 = blockIdx.x * 128;
    const float* X = z ? A : Q;

    stage_flat(WiC, WS, 54272, w, lane);   // async; overlaps X conversion

    const float4* xs4 = (const float4*)(X + (size_t)r0 * DD);
    for (int i = tid; i < 9600; i += 256) {
        int row = i / 75, c4 = (i - row * 75) * 4;
        float4 v = xs4[i];
        *(bf16x4*)(Xs + row * XSS + c4) =
            (bf16x4){(__bf16)v.x, (__bf16)v.y, (__bf16)v.z, (__bf16)v.w};
    }
    for (int i = tid; i < 128 * 7; i += 256) {
        int row = i / 7, c4 = 300 + (i - row * 7) * 4;
        *(bf16x4*)(Xs + row * XSS + c4) =
            (bf16x4){(__bf16)0.f, (__bf16)0.f, (__bf16)0.f, (__bf16)0.f};
    }
    __syncthreads();

    f32x16 ai[5], au[5];
#pragma unroll
    for (int t = 0; t < 5; t++) { ai[t] = z16(); au[t] = z16(); }
    bf16x8 af[10];

    for (int c = 0; c < 2; c++) {
        if (c) { __syncthreads(); stage_flat(WiC + WCE, WS, 54272, w, lane); __syncthreads(); }
#pragma unroll
        for (int ks = 0; ks < 10; ks++)
            af[ks] = *(const bf16x8*)(Xs + (w * 32 + m32) * XSS + c * 160 + ks * 16 + half * 8);
        for (int ks = 0; ks < 10; ks++)
#pragma unroll
            for (int t = 0; t < 5; t++)
                ai[t] = __builtin_amdgcn_mfma_f32_32x32x16_bf16(
                    af[ks], *(const bf16x8*)(WS + (t * 32 + m32) * KP + ks * 16 + half * 8),
                    ai[t], 0, 0, 0);
        __syncthreads();
        stage_flat(WuC + (size_t)c * WCE, WS, 54272, w, lane);
        __syncthreads();
        for (int ks = 0; ks < 10; ks++)
#pragma unroll
            for (int t = 0; t < 5; t++)
                au[t] = __builtin_amdgcn_mfma_f32_32x32x16_bf16(
                    af[ks], *(const bf16x8*)(WS + (t * 32 + m32) * KP + ks * 16 + half * 8),
                    au[t], 0, 0, 0);
    }

    // gate values into ai
#pragma unroll
    for (int t = 0; t < 5; t++) {
        int h = t * 32 + m32;
        int hc = h < HHH ? h : 0;
        float bih = bi[hc], buh = bu[hc];
#pragma unroll
        for (int r = 0; r < 16; r++) {
            float v = 0.f;
            if (h < HHH) {
                float xi = ai[t][r] + bih, xu = au[t][r] + buh;
                v = (1.f / (1.f + __expf(-xi))) * tanhf(xu);
            }
            ai[t][r] = v;
        }
    }

    if (z) {  // A-side: write AhB
#pragma unroll
        for (int t = 0; t < 5; t++) {
            int h = t * 32 + m32;
#pragma unroll
            for (int r = 0; r < 16; r++) {
                int rowp = (r & 3) + 8 * (r >> 2) + 4 * half;
                AhB[(size_t)(r0 + w * 32 + rowp) * KP + h] = (__bf16)ai[t][r];
            }
        }
        return;
    }

    // Q-side: Qh -> LDS twice (A-layout + transposed build buffer)
    __syncthreads();   // all waves done with Xs/WS
#pragma unroll
    for (int t = 0; t < 5; t++) {
        int h = t * 32 + m32;
#pragma unroll
        for (int r = 0; r < 16; r++) {
            int rowp = (r & 3) + 8 * (r >> 2) + 4 * half;
            int j = w * 32 + rowp;
            __bf16 v = (__bf16)ai[t][r];
            Xs[j * KP + h] = v;        // QhA [row][168]
            WS[h * JT + j] = v;        // QhTbuf [h][144]
        }
    }
    __syncthreads();
    const int b = r0 >> 11, qt0 = (r0 & 2047) >> 6;
    // copy QhT tiles (2 x [160][72]) to slab
    for (int i = tid; i < 2560; i += 256) {
        int tile = i / 1280, rr = i - tile * 1280;
        int hh = rr >> 3, seg = rr & 7;
        *(bf16x8*)(Slab + (size_t)(b * 32 + qt0 + tile) * SLAB_E + QHT_OFF_E + hh * QTS + seg * 8)
            = *(const bf16x8*)(WS + hh * JT + tile * 64 + seg * 8);
    }
    __syncthreads();
    stage_flat(WgT, WS, 54272, w, lane);
    __syncthreads();

    bf16x8 af2[10];
#pragma unroll
    for (int ks = 0; ks < 10; ks++)
        af2[ks] = *(const bf16x8*)(Xs + (w * 32 + m32) * KP + ks * 16 + half * 8);
    f32x16 qg[5];
#pragma unroll
    for (int t = 0; t < 5; t++) qg[t] = z16();
    for (int ks = 0; ks < 10; ks++)
#pragma unroll
        for (int t = 0; t < 5; t++)
            qg[t] = __builtin_amdgcn_mfma_f32_32x32x16_bf16(
                af2[ks], *(const bf16x8*)(WS + (t * 32 + m32) * KP + ks * 16 + half * 8),
                qg[t], 0, 0, 0);

#pragma unroll
    for (int t = 0; t < 5; t++) {
        int h = t * 32 + m32;
        int hc = h < HHH ? h : 0;
        float bgh = bg[hc];
#pragma unroll
        for (int r = 0; r < 16; r++) {
            int rowp = (r & 3) + 8 * (r >> 2) + 4 * half;
            int q = (r0 & 2047) + w * 32 + rowp;
            float v = (h < HHH) ? (qg[t][r] + bgh) : 0.f;
            Slab[(size_t)(b * 32 + (q >> 6)) * SLAB_E + (q & 63) * KP + h] = (__bf16)v;
        }
    }
}

// ---------------------------------------------------------------------------
// attn: flash attention over q, 32x32x16 MFMA, q-split partials.
// block = (128 a-rows, b, qhalf); wave w owns a-rows w*32..+31.
// Writes unnormalized O (bf16) + l (f32).
// ---------------------------------------------------------------------------
__global__ __launch_bounds__(256, 1) void attn_mfma(
    const __bf16* __restrict__ Slab, const __bf16* __restrict__ AhB,
    __bf16* __restrict__ O, float* __restrict__ L)
{
    __shared__ __align__(16) __bf16 AhS[128 * KP];    // 43008 B
    __shared__ __align__(16) __bf16 Buf[2][SLAB_E];   // 90112 B
    __shared__ __align__(16) __bf16 PS[128 * QTS];    // 18432 B
    const int tid = threadIdx.x;
    const int w = tid >> 6, lane = tid & 63;
    const int m32 = lane & 31, half = lane >> 5;
    const int b = blockIdx.y, qh = blockIdx.z;
    const int a0 = blockIdx.x * 128;

    stage_flat(AhB + (size_t)(b * LQ + a0) * KP, AhS, 43008, w, lane);
    const char* slabBase = (const char*)Slab + (size_t)(b * 32 + qh * 16) * SLAB_B;
    stage_flat(slabBase, Buf[0], SLAB_B, w, lane);
    __syncthreads();

    bf16x8 af[10];
#pragma unroll
    for (int ks = 0; ks < 10; ks++)
        af[ks] = *(const bf16x8*)(AhS + (w * 32 + m32) * KP + ks * 16 + half * 8);

    float lsum[16];
#pragma unroll
    for (int r = 0; r < 16; r++) lsum[r] = 0.f;
    f32x16 acc[5];
#pragma unroll
    for (int t = 0; t < 5; t++) acc[t] = z16();

    for (int qt = 0; qt < 16; qt++) {
        const int cur = qt & 1;
        if (qt < 15)
            stage_flat(slabBase + (size_t)(qt + 1) * SLAB_B, Buf[cur ^ 1], SLAB_B, w, lane);
        const __bf16* Bq = Buf[cur];
        const __bf16* Bv = Buf[cur] + QHT_OFF_E;

        // S = Ah(32a) x Qg(64q), K=160
        f32x16 s0 = z16(), s1 = z16();
        for (int ks = 0; ks < 10; ks++) {
            s0 = __builtin_amdgcn_mfma_f32_32x32x16_bf16(
                af[ks], *(const bf16x8*)(Bq + m32 * KP + ks * 16 + half * 8), s0, 0, 0, 0);
            s1 = __builtin_amdgcn_mfma_f32_32x32x16_bf16(
                af[ks], *(const bf16x8*)(Bq + (32 + m32) * KP + ks * 16 + half * 8), s1, 0, 0, 0);
        }
        // P = exp(S) -> PS (wave-private rows), accumulate l
#pragma unroll
        for (int r = 0; r < 16; r++) {
            int rowp = (r & 3) + 8 * (r >> 2) + 4 * half;
            float p0 = __expf(s0[r]);
            float p1 = __expf(s1[r]);
            lsum[r] += p0 + p1;
            PS[(w * 32 + rowp) * QTS + m32] = (__bf16)p0;
            PS[(w * 32 + rowp) * QTS + 32 + m32] = (__bf16)p1;
        }
        // O += P(32a x 64q) x QhT(64q x 160h)
#pragma unroll
        for (int kk = 0; kk < 4; kk++) {
            bf16x8 pf = *(const bf16x8*)(PS + (w * 32 + m32) * QTS + kk * 16 + half * 8);
#pragma unroll
            for (int t = 0; t < 5; t++)
                acc[t] = __builtin_amdgcn_mfma_f32_32x32x16_bf16(
                    pf, *(const bf16x8*)(Bv + (t * 32 + m32) * QTS + kk * 16 + half * 8),
                    acc[t], 0, 0, 0);
        }
        __syncthreads();  // drains prefetch; protects Buf reuse
    }

    // reduce l across the 32-lane column group
#pragma unroll
    for (int r = 0; r < 16; r++) {
        float s = lsum[r];
#pragma unroll
        for (int m = 1; m < 32; m <<= 1) s += __shfl_xor(s, m, 64);
        lsum[r] = s;
    }
    __bf16* Ob = O + (size_t)(qh * NROWS + b * LQ + a0) * 160;
#pragma unroll
    for (int t = 0; t < 5; t++) {
        int h = t * 32 + m32;
#pragma unroll
        for (int r = 0; r < 16; r++) {
            int rowp = (r & 3) + 8 * (r >> 2) + 4 * half;
            Ob[(size_t)(w * 32 + rowp) * 160 + h] = (__bf16)acc[t][r];
        }
    }
    if (m32 == 0) {
        float* Lb = L + qh * NROWS + b * LQ + a0 + w * 32;
#pragma unroll
        for (int r = 0; r < 16; r++) {
            int rowp = (r & 3) + 8 * (r >> 2) + 4 * half;
            Lb[rowp] = lsum[r];
        }
    }
}

// ---------------------------------------------------------------------------
// final: Hm = (O1+O2)/(l1+l2); Out = relu([Ah,Hm]@Wt + bt).
// block = 64 rows; waves: (m-tile = w&1, t-range split 3/2 = w>>1). 32x32x16.
// ---------------------------------------------------------------------------
__global__ __launch_bounds__(256, 1) void final_mfma(
    const __bf16* __restrict__ AhB, const __bf16* __restrict__ O,
    const float* __restrict__ L, const __bf16* __restrict__ Wt12,
    const float* __restrict__ bt, float* __restrict__ Out)
{
    __shared__ __align__(16) __bf16 AS[64 * KP];          // 21504 B
    __shared__ __align__(16) __bf16 HS[64 * KP];          // 21504 B
    __shared__ __align__(16) __bf16 WtS[2 * 160 * KP];    // 107520 B
    const int tid = threadIdx.x;
    const int w = tid >> 6, lane = tid & 63;
    const int m32 = lane & 31, half = lane >> 5;
    const int r0 = blockIdx.x * 64;

    stage_flat(AhB + (size_t)r0 * KP, AS, 21504, w, lane);
    stage_flat(Wt12, WtS, 107520, w, lane);

    // combine partials -> HS
    {
        int rhat = tid >> 2, qq = tid & 3;
        int grow = r0 + rhat;
        float inv = 1.f / (L[grow] + L[NROWS + grow]);
        const bf16x8* o1 = (const bf16x8*)(O + (size_t)grow * 160 + qq * 40);
        const bf16x8* o2 = (const bf16x8*)(O + (size_t)(NROWS + grow) * 160 + qq * 40);
#pragma unroll
        for (int k = 0; k < 5; k++) {
            bf16x8 x = o1[k], y = o2[k], hv;
#pragma unroll
            for (int j = 0; j < 8; j++)
                hv[j] = (__bf16)(((float)x[j] + (float)y[j]) * inv);
            *(bf16x8*)(HS + rhat * KP + qq * 40 + k * 8) = hv;
        }
    }
    __syncthreads();

    const int m = w & 1, th = w >> 1;
    const int tbase = th ? 3 : 0, tn = th ? 2 : 3;
    f32x16 acc[3];
#pragma unroll
    for (int i = 0; i < 3; i++) acc[i] = z16();

    for (int ch = 0; ch < 2; ch++) {
        const __bf16* src = ch ? HS : AS;
        for (int ks = 0; ks < 10; ks++) {
            bf16x8 af = *(const bf16x8*)(src + (m * 32 + m32) * KP + ks * 16 + half * 8);
#pragma unroll
            for (int ti = 0; ti < 3; ti++) {
                if (ti < tn) {
                    int t = tbase + ti;
                    acc[ti] = __builtin_amdgcn_mfma_f32_32x32x16_bf16(
                        af, *(const bf16x8*)(WtS + (ch * 160 + t * 32 + m32) * KP + ks * 16 + half * 8),
                        acc[ti], 0, 0, 0);
                }
            }
        }
    }

#pragma unroll
    for (int ti = 0; ti < 3; ti++) {
        if (ti < tn) {
            int t = tbase + ti;
            int h = t * 32 + m32;
            if (h < HHH) {
                float bth = bt[h];
#pragma unroll
                for (int r = 0; r < 16; r++) {
                    int rowp = (r & 3) + 8 * (r >> 2) + 4 * half;
                    float v = acc[ti][r] + bth;
                    Out[(size_t)(r0 + m * 32 + rowp) * HHH + h] = v > 0.f ? v : 0.f;
                }
            }
        }
    }
}

// ---------------------------------------------------------------------------
extern "C" void kernel_launch(void* const* d_in, const int* in_sizes, int n_in,
                              void* d_out, int out_size, void* d_ws, size_t ws_size,
                              hipStream_t stream)
{
    const float* Q  = (const float*)d_in[0];
    const float* A  = (const float*)d_in[1];
    const float* Wi = (const float*)d_in[2];
    const float* Wu = (const float*)d_in[3];
    const float* Wg = (const float*)d_in[4];
    const float* Wt = (const float*)d_in[5];
    const float* bi = (const float*)d_in[6];
    const float* bu = (const float*)d_in[7];
    const float* bg = (const float*)d_in[8];
    const float* bt = (const float*)d_in[9];
    float* out = (float*)d_out;

    char* ws = (char*)d_ws;
    __bf16* Slab = (__bf16*)(ws);                    // 11,534,336 B
    __bf16* AhB  = (__bf16*)(ws + 11534336);         //  5,505,024 B
    __bf16* Op   = (__bf16*)(ws + 17039360);         // 10,485,760 B
    float*  Lp   = (float*) (ws + 27525120);         //    131,072 B
    __bf16* WiC  = (__bf16*)(ws + 27656192);         //    108,544 B
    __bf16* WuC  = (__bf16*)(ws + 27764736);         //    108,544 B
    __bf16* WgT  = (__bf16*)(ws + 27873280);         //     54,272 B
    __bf16* Wt12 = (__bf16*)(ws + 27927552);         //    107,520 B

    convert_weights<<<dim3(212, 4), 256, 0, stream>>>(Wi, Wu, Wg, Wt,
                                                      WiC, WuC, WgT, Wt12);
    gatep<<<dim3(NROWS / 128, 2), 256, 0, stream>>>(Q, A, WiC, WuC, WgT,
                                                    bi, bu, bg, AhB, Slab);
    attn_mfma<<<dim3(16, BB, 2), 256, 0, stream>>>(Slab, AhB, Op, Lp);
    final_mfma<<<NROWS / 64, 256, 0, stream>>>(AhB, Op, Lp, Wt12, bt, out);
}

// Round 6
// 169.100 us; speedup vs baseline: 8.8633x; 1.1146x over previous
//
#include <hip/hip_runtime.h>
#include <math.h>

#define BB 8
#define LQ 2048
#define DD 300
#define HHH 150
#define NROWS (BB * LQ)

#define KP 168          // row stride (elems) for AhB / Qg / W rows (336 B)
#define QTS 72          // QhT q-stride and PS stride (144 B)
#define WCE 27136       // padded elems per W chunk (54,272 B; multiple of 1024)
#define SLAB_B 45056    // per-(b,qt) slab: [Qg 64x168 | pad 512B | QhT 160x72]
#define SLAB_E 22528
#define QHT_OFF_E 11008

typedef __bf16 bf16x8 __attribute__((ext_vector_type(8)));
typedef __bf16 bf16x4 __attribute__((ext_vector_type(4)));
typedef float f32x16 __attribute__((ext_vector_type(16)));

__device__ __forceinline__ void gl_lds16(const void* g, void* l) {
    __builtin_amdgcn_global_load_lds(
        (const __attribute__((address_space(1))) void*)g,
        (__attribute__((address_space(3))) void*)l,
        16, 0, 0);
}
// flat async global->LDS copy; bytes must be a multiple of 1024
__device__ __forceinline__ void stage_flat(const void* g, void* l, int bytes,
                                           int w, int lane) {
    for (int ofs = w * 1024; ofs < bytes; ofs += 4096)
        gl_lds16((const char*)g + ofs + lane * 16, (char*)l + ofs);
}
__device__ __forceinline__ f32x16 z16() {
    f32x16 v;
#pragma unroll
    for (int i = 0; i < 16; i++) v[i] = 0.f;
    return v;
}
__device__ __forceinline__ bf16x8 cvt8(float4 u, float4 v) {
    return (bf16x8){(__bf16)u.x, (__bf16)u.y, (__bf16)u.z, (__bf16)u.w,
                    (__bf16)v.x, (__bf16)v.y, (__bf16)v.z, (__bf16)v.w};
}

// ---------------------------------------------------------------------------
// Weight conversion. z=0/1: WiC/WuC [2 chunks][160h][168k] (chunk c = k 160c..),
// padded to WCE elems/chunk. z=2: WgT [160][168]+pad. z=3: Wt12 [2][160][168].
// ---------------------------------------------------------------------------
__global__ __launch_bounds__(256) void convert_weights(
    const float* __restrict__ Wi, const float* __restrict__ Wu,
    const float* __restrict__ Wg, const float* __restrict__ Wt,
    __bf16* __restrict__ WiC, __bf16* __restrict__ WuC,
    __bf16* __restrict__ WgT, __bf16* __restrict__ Wt12)
{
    const int z = blockIdx.y;
    const int i = blockIdx.x * 256 + threadIdx.x;
    if (z < 2) {
        if (i >= 2 * WCE) return;
        int c = i / WCE, rem = i - c * WCE;
        float v = 0.f;
        if (rem < 160 * KP) {
            int h = rem / KP, kc = rem - h * KP;
            int d = c * 160 + kc;
            if (kc < 160 && d < DD && h < HHH) v = (z ? Wu : Wi)[(size_t)d * HHH + h];
        }
        (z ? WuC : WiC)[i] = (__bf16)v;
    } else if (z == 2) {
        if (i >= WCE) return;
        float v = 0.f;
        if (i < 160 * KP) {
            int h = i / KP, kc = i - h * KP;
            if (kc < HHH && h < HHH) v = Wg[(size_t)kc * HHH + h];
        }
        WgT[i] = (__bf16)v;
    } else {
        if (i >= 2 * 160 * KP) return;
        int c = i / (160 * KP), rem = i - c * (160 * KP);
        int h = rem / KP, kc = rem - h * KP;
        float v = (kc < HHH && h < HHH) ? Wt[(size_t)(c * HHH + kc) * HHH + h] : 0.f;
        Wt12[i] = (__bf16)v;
    }
}

// ---------------------------------------------------------------------------
// gatep v2: direct-global A-fragments, double-buffered weight chunks.
// z=1: Ah = gate(A) -> AhB.  z=0: Qh = gate(Q) on-chip -> slab Qg + slab QhT.
// Block = 128 rows, wave w owns rows w*32..+31 (one 32-row m-tile), 32x32x16.
// ---------------------------------------------------------------------------
__global__ __launch_bounds__(256, 1) void gatep(
    const float* __restrict__ Q, const float* __restrict__ A,
    const __bf16* __restrict__ WiC, const __bf16* __restrict__ WuC,
    const __bf16* __restrict__ WgT,
    const float* __restrict__ bi, const float* __restrict__ bu,
    const float* __restrict__ bg,
    __bf16* __restrict__ AhB, __bf16* __restrict__ Slab)
{
    __shared__ __align__(16) __bf16 WB[2][WCE];      // 2 x 54,272 B
    __shared__ __align__(16) __bf16 QhA[128 * KP];   // 43,008 B (z=0 only)
    const int tid = threadIdx.x;
    const int w = tid >> 6, lane = tid & 63;
    const int m32 = lane & 31, half = lane >> 5;
    const int z = blockIdx.y;
    const int r0 = blockIdx.x * 128;
    const float* X = z ? A : Q;

    stage_flat(WiC, WB[0], 54272, w, lane);   // async; overlaps frag loads

    // ---- chunk-0 A-fragments straight from global (fp32 -> bf16) ----
    const float* xrow = X + (size_t)(r0 + w * 32 + m32) * DD + half * 8;
    bf16x8 af0[10], af1[10];
#pragma unroll
    for (int ks = 0; ks < 10; ks++) {
        float4 u = *(const float4*)(xrow + ks * 16);
        float4 v = *(const float4*)(xrow + ks * 16 + 4);
        af0[ks] = cvt8(u, v);
    }

    f32x16 ai[5], au[5];
#pragma unroll
    for (int t = 0; t < 5; t++) { ai[t] = z16(); au[t] = z16(); }

    __syncthreads();                                   // WB0 = Wi-c0 ready
    stage_flat(WuC, WB[1], 54272, w, lane);

    // chunk-1 fragments (issued now; drain at next barrier, hidden by MFMA)
#pragma unroll
    for (int ks = 0; ks < 8; ks++) {
        float4 u = *(const float4*)(xrow + 160 + ks * 16);
        float4 v = *(const float4*)(xrow + 160 + ks * 16 + 4);
        af1[ks] = cvt8(u, v);
    }
    {   // ks=8: k = 288+half*8 .. ; half=1 tail (k>=300) masked (weights zero there)
        float4 u = *(const float4*)(xrow + 288);
        float4 v = (half == 0) ? *(const float4*)(xrow + 292) : (float4){0.f, 0.f, 0.f, 0.f};
        af1[8] = cvt8(u, v);
        af1[9] = (bf16x8){(__bf16)0.f, (__bf16)0.f, (__bf16)0.f, (__bf16)0.f,
                          (__bf16)0.f, (__bf16)0.f, (__bf16)0.f, (__bf16)0.f};
    }

    for (int ks = 0; ks < 10; ks++)
#pragma unroll
        for (int t = 0; t < 5; t++)
            ai[t] = __builtin_amdgcn_mfma_f32_32x32x16_bf16(
                af0[ks], *(const bf16x8*)(WB[0] + (t * 32 + m32) * KP + ks * 16 + half * 8),
                ai[t], 0, 0, 0);
    __syncthreads();                                   // WB1 = Wu-c0 ready
    stage_flat(WiC + WCE, WB[0], 54272, w, lane);
    for (int ks = 0; ks < 10; ks++)
#pragma unroll
        for (int t = 0; t < 5; t++)
            au[t] = __builtin_amdgcn_mfma_f32_32x32x16_bf16(
                af0[ks], *(const bf16x8*)(WB[1] + (t * 32 + m32) * KP + ks * 16 + half * 8),
                au[t], 0, 0, 0);
    __syncthreads();                                   // WB0 = Wi-c1 ready
    stage_flat(WuC + WCE, WB[1], 54272, w, lane);
    for (int ks = 0; ks < 10; ks++)
#pragma unroll
        for (int t = 0; t < 5; t++)
            ai[t] = __builtin_amdgcn_mfma_f32_32x32x16_bf16(
                af1[ks], *(const bf16x8*)(WB[0] + (t * 32 + m32) * KP + ks * 16 + half * 8),
                ai[t], 0, 0, 0);
    __syncthreads();                                   // WB1 = Wu-c1 ready
    if (z == 0) stage_flat(WgT, WB[0], 54272, w, lane);  // prefetch Wg
    for (int ks = 0; ks < 10; ks++)
#pragma unroll
        for (int t = 0; t < 5; t++)
            au[t] = __builtin_amdgcn_mfma_f32_32x32x16_bf16(
                af1[ks], *(const bf16x8*)(WB[1] + (t * 32 + m32) * KP + ks * 16 + half * 8),
                au[t], 0, 0, 0);

    // ---- gate epilogue: v = sigmoid(ai+bi) * tanh(au+bu) (fast exp forms) ----
#pragma unroll
    for (int t = 0; t < 5; t++) {
        int h = t * 32 + m32;
        int hc = h < HHH ? h : 0;
        float bih = bi[hc], buh = bu[hc];
#pragma unroll
        for (int r = 0; r < 16; r++) {
            float v = 0.f;
            if (h < HHH) {
                float xi = ai[t][r] + bih, xu = au[t][r] + buh;
                float s = 1.f / (1.f + __expf(-xi));
                float tt = 1.f - 2.f / (1.f + __expf(2.f * xu));
                v = s * tt;
            }
            ai[t][r] = v;
        }
    }

    if (z) {  // A-side: write AhB and exit
#pragma unroll
        for (int t = 0; t < 5; t++) {
            int h = t * 32 + m32;
#pragma unroll
            for (int r = 0; r < 16; r++) {
                int rowp = (r & 3) + 8 * (r >> 2) + 4 * half;
                AhB[(size_t)(r0 + w * 32 + rowp) * KP + h] = (__bf16)ai[t][r];
            }
        }
        return;
    }

    // ---- Q-side: Qh -> LDS (wave-private rows), then Qg MFMA + QhT scatter ----
#pragma unroll
    for (int t = 0; t < 5; t++) {
        int h = t * 32 + m32;
#pragma unroll
        for (int r = 0; r < 16; r++) {
            int rowp = (r & 3) + 8 * (r >> 2) + 4 * half;
            QhA[(w * 32 + rowp) * KP + h] = (__bf16)ai[t][r];
        }
    }
    // A-frags for Qg: rows w*32..+31 were written by this wave (lgkm-ordered)
    bf16x8 afq[10];
#pragma unroll
    for (int ks = 0; ks < 10; ks++)
        afq[ks] = *(const bf16x8*)(QhA + (w * 32 + m32) * KP + ks * 16 + half * 8);
    __syncthreads();   // Wg in WB0 ready; QhA visible block-wide

    f32x16 qg[5];
#pragma unroll
    for (int t = 0; t < 5; t++) qg[t] = z16();
    for (int ks = 0; ks < 10; ks++)
#pragma unroll
        for (int t = 0; t < 5; t++)
            qg[t] = __builtin_amdgcn_mfma_f32_32x32x16_bf16(
                afq[ks], *(const bf16x8*)(WB[0] + (t * 32 + m32) * KP + ks * 16 + half * 8),
                qg[t], 0, 0, 0);

    const int b = r0 >> 11, qt0 = (r0 & 2047) >> 6;
#pragma unroll
    for (int t = 0; t < 5; t++) {
        int h = t * 32 + m32;
        int hc = h < HHH ? h : 0;
        float bgh = bg[hc];
#pragma unroll
        for (int r = 0; r < 16; r++) {
            int rowp = (r & 3) + 8 * (r >> 2) + 4 * half;
            int q = (r0 & 2047) + w * 32 + rowp;
            float v = (h < HHH) ? (qg[t][r] + bgh) : 0.f;
            Slab[(size_t)(b * 32 + (q >> 6)) * SLAB_E + (q & 63) * KP + h] = (__bf16)v;
        }
    }

    // QhT transpose-scatter: LDS b128 reads -> coalesced 128-B short-store rows
    {
        const int jl = tid & 63, tile = (tid >> 6) & 1, hgrp = tid >> 7;
        for (int hseg = hgrp; hseg < 20; hseg += 2) {
            bf16x8 vv = *(const bf16x8*)(QhA + (tile * 64 + jl) * KP + hseg * 8);
            __bf16* dst = Slab + (size_t)(b * 32 + qt0 + tile) * SLAB_E + QHT_OFF_E + jl;
#pragma unroll
            for (int e = 0; e < 8; e++)
                dst[(hseg * 8 + e) * QTS] = vv[e];
        }
    }
}

// ---------------------------------------------------------------------------
// attn: flash attention over q, 32x32x16 MFMA, q-split partials.
// block = (128 a-rows, b, qhalf); wave w owns a-rows w*32..+31.
// Writes unnormalized O (bf16) + l (f32).
// ---------------------------------------------------------------------------
__global__ __launch_bounds__(256, 1) void attn_mfma(
    const __bf16* __restrict__ Slab, const __bf16* __restrict__ AhB,
    __bf16* __restrict__ O, float* __restrict__ L)
{
    __shared__ __align__(16) __bf16 AhS[128 * KP];    // 43008 B
    __shared__ __align__(16) __bf16 Buf[2][SLAB_E];   // 90112 B
    __shared__ __align__(16) __bf16 PS[128 * QTS];    // 18432 B
    const int tid = threadIdx.x;
    const int w = tid >> 6, lane = tid & 63;
    const int m32 = lane & 31, half = lane >> 5;
    const int b = blockIdx.y, qh = blockIdx.z;
    const int a0 = blockIdx.x * 128;

    stage_flat(AhB + (size_t)(b * LQ + a0) * KP, AhS, 43008, w, lane);
    const char* slabBase = (const char*)Slab + (size_t)(b * 32 + qh * 16) * SLAB_B;
    stage_flat(slabBase, Buf[0], SLAB_B, w, lane);
    __syncthreads();

    bf16x8 af[10];
#pragma unroll
    for (int ks = 0; ks < 10; ks++)
        af[ks] = *(const bf16x8*)(AhS + (w * 32 + m32) * KP + ks * 16 + half * 8);

    float lsum[16];
#pragma unroll
    for (int r = 0; r < 16; r++) lsum[r] = 0.f;
    f32x16 acc[5];
#pragma unroll
    for (int t = 0; t < 5; t++) acc[t] = z16();

    for (int qt = 0; qt < 16; qt++) {
        const int cur = qt & 1;
        if (qt < 15)
            stage_flat(slabBase + (size_t)(qt + 1) * SLAB_B, Buf[cur ^ 1], SLAB_B, w, lane);
        const __bf16* Bq = Buf[cur];
        const __bf16* Bv = Buf[cur] + QHT_OFF_E;

        // S = Ah(32a) x Qg(64q), K=160
        f32x16 s0 = z16(), s1 = z16();
        for (int ks = 0; ks < 10; ks++) {
            s0 = __builtin_amdgcn_mfma_f32_32x32x16_bf16(
                af[ks], *(const bf16x8*)(Bq + m32 * KP + ks * 16 + half * 8), s0, 0, 0, 0);
            s1 = __builtin_amdgcn_mfma_f32_32x32x16_bf16(
                af[ks], *(const bf16x8*)(Bq + (32 + m32) * KP + ks * 16 + half * 8), s1, 0, 0, 0);
        }
        // P = exp(S) -> PS (wave-private rows), accumulate l
#pragma unroll
        for (int r = 0; r < 16; r++) {
            int rowp = (r & 3) + 8 * (r >> 2) + 4 * half;
            float p0 = __expf(s0[r]);
            float p1 = __expf(s1[r]);
            lsum[r] += p0 + p1;
            PS[(w * 32 + rowp) * QTS + m32] = (__bf16)p0;
            PS[(w * 32 + rowp) * QTS + 32 + m32] = (__bf16)p1;
        }
        // O += P(32a x 64q) x QhT(64q x 160h)
#pragma unroll
        for (int kk = 0; kk < 4; kk++) {
            bf16x8 pf = *(const bf16x8*)(PS + (w * 32 + m32) * QTS + kk * 16 + half * 8);
#pragma unroll
            for (int t = 0; t < 5; t++)
                acc[t] = __builtin_amdgcn_mfma_f32_32x32x16_bf16(
                    pf, *(const bf16x8*)(Bv + (t * 32 + m32) * QTS + kk * 16 + half * 8),
                    acc[t], 0, 0, 0);
        }
        __syncthreads();  // drains prefetch; protects Buf reuse
    }

    // reduce l across the 32-lane column group
#pragma unroll
    for (int r = 0; r < 16; r++) {
        float s = lsum[r];
#pragma unroll
        for (int m = 1; m < 32; m <<= 1) s += __shfl_xor(s, m, 64);
        lsum[r] = s;
    }
    __bf16* Ob = O + (size_t)(qh * NROWS + b * LQ + a0) * 160;
#pragma unroll
    for (int t = 0; t < 5; t++) {
        int h = t * 32 + m32;
#pragma unroll
        for (int r = 0; r < 16; r++) {
            int rowp = (r & 3) + 8 * (r >> 2) + 4 * half;
            Ob[(size_t)(w * 32 + rowp) * 160 + h] = (__bf16)acc[t][r];
        }
    }
    if (m32 == 0) {
        float* Lb = L + qh * NROWS + b * LQ + a0 + w * 32;
#pragma unroll
        for (int r = 0; r < 16; r++) {
            int rowp = (r & 3) + 8 * (r >> 2) + 4 * half;
            Lb[rowp] = lsum[r];
        }
    }
}

// ---------------------------------------------------------------------------
// final: Hm = (O1+O2)/(l1+l2); Out = relu([Ah,Hm]@Wt + bt).
// block = 64 rows; waves: (m-tile = w&1, t-range split 3/2 = w>>1). 32x32x16.
// ---------------------------------------------------------------------------
__global__ __launch_bounds__(256, 1) void final_mfma(
    const __bf16* __restrict__ AhB, const __bf16* __restrict__ O,
    const float* __restrict__ L, const __bf16* __restrict__ Wt12,
    const float* __restrict__ bt, float* __restrict__ Out)
{
    __shared__ __align__(16) __bf16 AS[64 * KP];          // 21504 B
    __shared__ __align__(16) __bf16 HS[64 * KP];          // 21504 B
    __shared__ __align__(16) __bf16 WtS[2 * 160 * KP];    // 107520 B
    const int tid = threadIdx.x;
    const int w = tid >> 6, lane = tid & 63;
    const int m32 = lane & 31, half = lane >> 5;
    const int r0 = blockIdx.x * 64;

    stage_flat(AhB + (size_t)r0 * KP, AS, 21504, w, lane);
    stage_flat(Wt12, WtS, 107520, w, lane);

    // combine partials -> HS
    {
        int rhat = tid >> 2, qq = tid & 3;
        int grow = r0 + rhat;
        float inv = 1.f / (L[grow] + L[NROWS + grow]);
        const bf16x8* o1 = (const bf16x8*)(O + (size_t)grow * 160 + qq * 40);
        const bf16x8* o2 = (const bf16x8*)(O + (size_t)(NROWS + grow) * 160 + qq * 40);
#pragma unroll
        for (int k = 0; k < 5; k++) {
            bf16x8 x = o1[k], y = o2[k], hv;
#pragma unroll
            for (int j = 0; j < 8; j++)
                hv[j] = (__bf16)(((float)x[j] + (float)y[j]) * inv);
            *(bf16x8*)(HS + rhat * KP + qq * 40 + k * 8) = hv;
        }
    }
    __syncthreads();

    const int m = w & 1, th = w >> 1;
    const int tbase = th ? 3 : 0, tn = th ? 2 : 3;
    f32x16 acc[3];
#pragma unroll
    for (int i = 0; i < 3; i++) acc[i] = z16();

    for (int ch = 0; ch < 2; ch++) {
        const __bf16* src = ch ? HS : AS;
        for (int ks = 0; ks < 10; ks++) {
            bf16x8 af = *(const bf16x8*)(src + (m * 32 + m32) * KP + ks * 16 + half * 8);
#pragma unroll
            for (int ti = 0; ti < 3; ti++) {
                if (ti < tn) {
                    int t = tbase + ti;
                    acc[ti] = __builtin_amdgcn_mfma_f32_32x32x16_bf16(
                        af, *(const bf16x8*)(WtS + (ch * 160 + t * 32 + m32) * KP + ks * 16 + half * 8),
                        acc[ti], 0, 0, 0);
                }
            }
        }
    }

#pragma unroll
    for (int ti = 0; ti < 3; ti++) {
        if (ti < tn) {
            int t = tbase + ti;
            int h = t * 32 + m32;
            if (h < HHH) {
                float bth = bt[h];
#pragma unroll
                for (int r = 0; r < 16; r++) {
                    int rowp = (r & 3) + 8 * (r >> 2) + 4 * half;
                    float v = acc[ti][r] + bth;
                    Out[(size_t)(r0 + m * 32 + rowp) * HHH + h] = v > 0.f ? v : 0.f;
                }
            }
        }
    }
}

// ---------------------------------------------------------------------------
extern "C" void kernel_launch(void* const* d_in, const int* in_sizes, int n_in,
                              void* d_out, int out_size, void* d_ws, size_t ws_size,
                              hipStream_t stream)
{
    const float* Q  = (const float*)d_in[0];
    const float* A  = (const float*)d_in[1];
    const float* Wi = (const float*)d_in[2];
    const float* Wu = (const float*)d_in[3];
    const float* Wg = (const float*)d_in[4];
    const float* Wt = (const float*)d_in[5];
    const float* bi = (const float*)d_in[6];
    const float* bu = (const float*)d_in[7];
    const float* bg = (const float*)d_in[8];
    const float* bt = (const float*)d_in[9];
    float* out = (float*)d_out;

    char* ws = (char*)d_ws;
    __bf16* Slab = (__bf16*)(ws);                    // 11,534,336 B
    __bf16* AhB  = (__bf16*)(ws + 11534336);         //  5,505,024 B
    __bf16* Op   = (__bf16*)(ws + 17039360);         // 10,485,760 B
    float*  Lp   = (float*) (ws + 27525120);         //    131,072 B
    __bf16* WiC  = (__bf16*)(ws + 27656192);         //    108,544 B
    __bf16* WuC  = (__bf16*)(ws + 27764736);         //    108,544 B
    __bf16* WgT  = (__bf16*)(ws + 27873280);         //     54,272 B
    __bf16* Wt12 = (__bf16*)(ws + 27927552);         //    107,520 B

    convert_weights<<<dim3(212, 4), 256, 0, stream>>>(Wi, Wu, Wg, Wt,
                                                      WiC, WuC, WgT, Wt12);
    gatep<<<dim3(NROWS / 128, 2), 256, 0, stream>>>(Q, A, WiC, WuC, WgT,
                                                    bi, bu, bg, AhB, Slab);
    attn_mfma<<<dim3(16, BB, 2), 256, 0, stream>>>(Slab, AhB, Op, Lp);
    final_mfma<<<NROWS / 64, 256, 0, stream>>>(AhB, Op, Lp, Wt12, bt, out);
}

// Round 7
// 167.268 us; speedup vs baseline: 8.9603x; 1.0110x over previous
//
#include <hip/hip_runtime.h>
#include <math.h>

#define BB 8
#define LQ 2048
#define DD 300
#define HHH 150
#define NROWS (BB * LQ)

#define KP 168          // row stride (elems) for AhB / Qg / W rows (336 B)
#define QTS 72          // QhT q-stride and PS stride (144 B)
#define WCE 27136       // padded elems per W chunk (54,272 B; multiple of 1024)
#define SLAB_B 45056    // per-(b,qt) slab: [Qg 64x168 | pad 512B | QhT 160x72]
#define SLAB_E 22528
#define QHT_OFF_E 11008

typedef __bf16 bf16x8 __attribute__((ext_vector_type(8)));
typedef __bf16 bf16x4 __attribute__((ext_vector_type(4)));
typedef float f32x16 __attribute__((ext_vector_type(16)));

__device__ __forceinline__ void gl_lds16(const void* g, void* l) {
    __builtin_amdgcn_global_load_lds(
        (const __attribute__((address_space(1))) void*)g,
        (__attribute__((address_space(3))) void*)l,
        16, 0, 0);
}
// flat async global->LDS copy, 4-wave (256-thr) blocks
__device__ __forceinline__ void stage_flat(const void* g, void* l, int bytes,
                                           int w, int lane) {
    for (int ofs = w * 1024; ofs < bytes; ofs += 4096)
        gl_lds16((const char*)g + ofs + lane * 16, (char*)l + ofs);
}
// flat async global->LDS copy, 8-wave (512-thr) blocks
__device__ __forceinline__ void stage_flat8(const void* g, void* l, int bytes,
                                            int w, int lane) {
    for (int ofs = w * 1024; ofs < bytes; ofs += 8192)
        gl_lds16((const char*)g + ofs + lane * 16, (char*)l + ofs);
}
__device__ __forceinline__ f32x16 z16() {
    f32x16 v;
#pragma unroll
    for (int i = 0; i < 16; i++) v[i] = 0.f;
    return v;
}
__device__ __forceinline__ bf16x8 cvt8(float4 u, float4 v) {
    return (bf16x8){(__bf16)u.x, (__bf16)u.y, (__bf16)u.z, (__bf16)u.w,
                    (__bf16)v.x, (__bf16)v.y, (__bf16)v.z, (__bf16)v.w};
}

// ---------------------------------------------------------------------------
// Weight conversion. z=0/1: WiC/WuC [2 chunks][160h][168k]; z=2: WgT; z=3: Wt12.
// ---------------------------------------------------------------------------
__global__ __launch_bounds__(256) void convert_weights(
    const float* __restrict__ Wi, const float* __restrict__ Wu,
    const float* __restrict__ Wg, const float* __restrict__ Wt,
    __bf16* __restrict__ WiC, __bf16* __restrict__ WuC,
    __bf16* __restrict__ WgT, __bf16* __restrict__ Wt12)
{
    const int z = blockIdx.y;
    const int i = blockIdx.x * 256 + threadIdx.x;
    if (z < 2) {
        if (i >= 2 * WCE) return;
        int c = i / WCE, rem = i - c * WCE;
        float v = 0.f;
        if (rem < 160 * KP) {
            int h = rem / KP, kc = rem - h * KP;
            int d = c * 160 + kc;
            if (kc < 160 && d < DD && h < HHH) v = (z ? Wu : Wi)[(size_t)d * HHH + h];
        }
        (z ? WuC : WiC)[i] = (__bf16)v;
    } else if (z == 2) {
        if (i >= WCE) return;
        float v = 0.f;
        if (i < 160 * KP) {
            int h = i / KP, kc = i - h * KP;
            if (kc < HHH && h < HHH) v = Wg[(size_t)kc * HHH + h];
        }
        WgT[i] = (__bf16)v;
    } else {
        if (i >= 2 * 160 * KP) return;
        int c = i / (160 * KP), rem = i - c * (160 * KP);
        int h = rem / KP, kc = rem - h * KP;
        float v = (kc < HHH && h < HHH) ? Wt[(size_t)(c * HHH + kc) * HHH + h] : 0.f;
        Wt12[i] = (__bf16)v;
    }
}

// ---------------------------------------------------------------------------
// gatep v3: 512 thr / 8 waves (2 per SIMD). Wave (wm = w&3, wn = w>>2):
// rows wm*32..+31, h-tiles tof..tof+tn-1 (3/2 ragged split).
// z=1: Ah = gate(A) -> AhB.  z=0: Qh on-chip -> slab Qg + slab QhT.
// ---------------------------------------------------------------------------
__global__ __launch_bounds__(512, 2) void gatep(
    const float* __restrict__ Q, const float* __restrict__ A,
    const __bf16* __restrict__ WiC, const __bf16* __restrict__ WuC,
    const __bf16* __restrict__ WgT,
    const float* __restrict__ bi, const float* __restrict__ bu,
    const float* __restrict__ bg,
    __bf16* __restrict__ AhB, __bf16* __restrict__ Slab)
{
    __shared__ __align__(16) __bf16 WB[2][WCE];      // 108,544 B
    __shared__ __align__(16) __bf16 QhA[128 * KP];   //  43,008 B
    const int tid = threadIdx.x;
    const int w = tid >> 6, lane = tid & 63;
    const int m32 = lane & 31, half = lane >> 5;
    const int wm = w & 3, wn = w >> 2;
    const int tof = wn ? 3 : 0, tn = wn ? 2 : 3;
    const int z = blockIdx.y;
    const int r0 = blockIdx.x * 128;
    const float* X = z ? A : Q;

    stage_flat8(WiC, WB[0], 54272, w, lane);   // async; overlaps frag loads

    // ---- chunk-0 A-fragments straight from global (fp32 -> bf16) ----
    const float* xrow = X + (size_t)(r0 + wm * 32 + m32) * DD + half * 8;
    bf16x8 af0[10], af1[10];
#pragma unroll
    for (int ks = 0; ks < 10; ks++) {
        float4 u = *(const float4*)(xrow + ks * 16);
        float4 v = *(const float4*)(xrow + ks * 16 + 4);
        af0[ks] = cvt8(u, v);
    }

    f32x16 ai[3], au[3];
#pragma unroll
    for (int t = 0; t < 3; t++) { ai[t] = z16(); au[t] = z16(); }

    __syncthreads();                                   // WB0 = Wi-c0 ready
    stage_flat8(WuC, WB[1], 54272, w, lane);

    // chunk-1 fragments (hidden under ai-c0 MFMA phase)
#pragma unroll
    for (int ks = 0; ks < 8; ks++) {
        float4 u = *(const float4*)(xrow + 160 + ks * 16);
        float4 v = *(const float4*)(xrow + 160 + ks * 16 + 4);
        af1[ks] = cvt8(u, v);
    }
    {   // ks=8 tail: k>=300 masked (weights are zero there anyway)
        float4 u = *(const float4*)(xrow + 288);
        float4 v = (half == 0) ? *(const float4*)(xrow + 292) : (float4){0.f, 0.f, 0.f, 0.f};
        af1[8] = cvt8(u, v);
        af1[9] = (bf16x8){(__bf16)0.f, (__bf16)0.f, (__bf16)0.f, (__bf16)0.f,
                          (__bf16)0.f, (__bf16)0.f, (__bf16)0.f, (__bf16)0.f};
    }

    for (int ks = 0; ks < 10; ks++)
#pragma unroll
        for (int ti = 0; ti < 3; ti++)
            if (ti < tn)
                ai[ti] = __builtin_amdgcn_mfma_f32_32x32x16_bf16(
                    af0[ks], *(const bf16x8*)(WB[0] + ((tof + ti) * 32 + m32) * KP + ks * 16 + half * 8),
                    ai[ti], 0, 0, 0);
    __syncthreads();                                   // WB1 = Wu-c0 ready
    stage_flat8(WiC + WCE, WB[0], 54272, w, lane);
    for (int ks = 0; ks < 10; ks++)
#pragma unroll
        for (int ti = 0; ti < 3; ti++)
            if (ti < tn)
                au[ti] = __builtin_amdgcn_mfma_f32_32x32x16_bf16(
                    af0[ks], *(const bf16x8*)(WB[1] + ((tof + ti) * 32 + m32) * KP + ks * 16 + half * 8),
                    au[ti], 0, 0, 0);
    __syncthreads();                                   // WB0 = Wi-c1 ready
    stage_flat8(WuC + WCE, WB[1], 54272, w, lane);
    for (int ks = 0; ks < 10; ks++)
#pragma unroll
        for (int ti = 0; ti < 3; ti++)
            if (ti < tn)
                ai[ti] = __builtin_amdgcn_mfma_f32_32x32x16_bf16(
                    af1[ks], *(const bf16x8*)(WB[0] + ((tof + ti) * 32 + m32) * KP + ks * 16 + half * 8),
                    ai[ti], 0, 0, 0);
    __syncthreads();                                   // WB1 = Wu-c1 ready
    if (z == 0) stage_flat8(WgT, WB[0], 54272, w, lane);  // prefetch Wg
    for (int ks = 0; ks < 10; ks++)
#pragma unroll
        for (int ti = 0; ti < 3; ti++)
            if (ti < tn)
                au[ti] = __builtin_amdgcn_mfma_f32_32x32x16_bf16(
                    af1[ks], *(const bf16x8*)(WB[1] + ((tof + ti) * 32 + m32) * KP + ks * 16 + half * 8),
                    au[ti], 0, 0, 0);

    // ---- gate epilogue ----
#pragma unroll
    for (int ti = 0; ti < 3; ti++) {
        if (ti >= tn) continue;
        int h = (tof + ti) * 32 + m32;
        int hc = h < HHH ? h : 0;
        float bih = bi[hc], buh = bu[hc];
#pragma unroll
        for (int r = 0; r < 16; r++) {
            float v = 0.f;
            if (h < HHH) {
                float xi = ai[ti][r] + bih, xu = au[ti][r] + buh;
                float s = 1.f / (1.f + __expf(-xi));
                float tt = 1.f - 2.f / (1.f + __expf(2.f * xu));
                v = s * tt;
            }
            ai[ti][r] = v;
        }
    }

    if (z) {  // A-side: write AhB and exit
#pragma unroll
        for (int ti = 0; ti < 3; ti++) {
            if (ti >= tn) continue;
            int h = (tof + ti) * 32 + m32;
#pragma unroll
            for (int r = 0; r < 16; r++) {
                int rowp = (r & 3) + 8 * (r >> 2) + 4 * half;
                AhB[(size_t)(r0 + wm * 32 + rowp) * KP + h] = (__bf16)ai[ti][r];
            }
        }
        return;
    }

    // ---- Q-side: Qh -> LDS (rows shared across wn halves) ----
#pragma unroll
    for (int ti = 0; ti < 3; ti++) {
        if (ti >= tn) continue;
        int h = (tof + ti) * 32 + m32;
#pragma unroll
        for (int r = 0; r < 16; r++) {
            int rowp = (r & 3) + 8 * (r >> 2) + 4 * half;
            QhA[(wm * 32 + rowp) * KP + h] = (__bf16)ai[ti][r];
        }
    }
    __syncthreads();   // QhA visible block-wide; Wg in WB0 ready

    bf16x8 afq[10];
#pragma unroll
    for (int ks = 0; ks < 10; ks++)
        afq[ks] = *(const bf16x8*)(QhA + (wm * 32 + m32) * KP + ks * 16 + half * 8);

    f32x16 qg[3];
#pragma unroll
    for (int t = 0; t < 3; t++) qg[t] = z16();
    for (int ks = 0; ks < 10; ks++)
#pragma unroll
        for (int ti = 0; ti < 3; ti++)
            if (ti < tn)
                qg[ti] = __builtin_amdgcn_mfma_f32_32x32x16_bf16(
                    afq[ks], *(const bf16x8*)(WB[0] + ((tof + ti) * 32 + m32) * KP + ks * 16 + half * 8),
                    qg[ti], 0, 0, 0);

    const int b = r0 >> 11, qt0 = (r0 & 2047) >> 6;
#pragma unroll
    for (int ti = 0; ti < 3; ti++) {
        if (ti >= tn) continue;
        int h = (tof + ti) * 32 + m32;
        int hc = h < HHH ? h : 0;
        float bgh = bg[hc];
#pragma unroll
        for (int r = 0; r < 16; r++) {
            int rowp = (r & 3) + 8 * (r >> 2) + 4 * half;
            int q = (r0 & 2047) + wm * 32 + rowp;
            float v = (h < HHH) ? (qg[ti][r] + bgh) : 0.f;
            Slab[(size_t)(b * 32 + (q >> 6)) * SLAB_E + (q & 63) * KP + h] = (__bf16)v;
        }
    }

    // QhT transpose-scatter (512 threads)
    {
        const int jl = tid & 63, tile = (tid >> 6) & 1, hgrp = tid >> 7;
        for (int hseg = hgrp; hseg < 20; hseg += 4) {
            bf16x8 vv = *(const bf16x8*)(QhA + (tile * 64 + jl) * KP + hseg * 8);
            __bf16* dst = Slab + (size_t)(b * 32 + qt0 + tile) * SLAB_E + QHT_OFF_E + jl;
#pragma unroll
            for (int e = 0; e < 8; e++)
                dst[(hseg * 8 + e) * QTS] = vv[e];
        }
    }
}

// ---------------------------------------------------------------------------
// attn v3: 512 thr / 8 waves (2 per SIMD). Wave (wa = w&3, wx = w>>2):
// S: a-rows wa*32..+31 x q-cols wx*32..+31; PV: same rows, q-half wx, full h.
// PS fully wave-private. O/l written as partial (qh*2+wx); combined in final.
// A-fragments gathered directly from global (no AhS buffer).
// ---------------------------------------------------------------------------
__global__ __launch_bounds__(512, 2) void attn_mfma(
    const __bf16* __restrict__ Slab, const __bf16* __restrict__ AhB,
    __bf16* __restrict__ O, float* __restrict__ L)
{
    __shared__ __align__(16) __bf16 Buf[2][SLAB_E];   // 90,112 B
    __shared__ __align__(16) __bf16 PS[128 * QTS];    // 18,432 B
    const int tid = threadIdx.x;
    const int w = tid >> 6, lane = tid & 63;
    const int m32 = lane & 31, half = lane >> 5;
    const int wa = w & 3, wx = w >> 2;
    const int b = blockIdx.y, qh = blockIdx.z;
    const int a0 = blockIdx.x * 128;

    const char* slabBase = (const char*)Slab + (size_t)(b * 32 + qh * 16) * SLAB_B;
    stage_flat8(slabBase, Buf[0], SLAB_B, w, lane);

    // A-fragments from global (row gather, once per kernel)
    const __bf16* arow = AhB + (size_t)(b * LQ + a0 + wa * 32 + m32) * KP + half * 8;
    bf16x8 af[10];
#pragma unroll
    for (int ks = 0; ks < 10; ks++)
        af[ks] = *(const bf16x8*)(arow + ks * 16);

    float lsum[16];
#pragma unroll
    for (int r = 0; r < 16; r++) lsum[r] = 0.f;
    f32x16 acc[5];
#pragma unroll
    for (int t = 0; t < 5; t++) acc[t] = z16();
    __syncthreads();

    for (int qt = 0; qt < 16; qt++) {
        const int cur = qt & 1;
        if (qt < 15)
            stage_flat8(slabBase + (size_t)(qt + 1) * SLAB_B, Buf[cur ^ 1], SLAB_B, w, lane);
        const __bf16* Bq = Buf[cur];
        const __bf16* Bv = Buf[cur] + QHT_OFF_E;

        // S = Ah(32a) x Qg(32q of this wx), K=160
        f32x16 s = z16();
        for (int ks = 0; ks < 10; ks++)
            s = __builtin_amdgcn_mfma_f32_32x32x16_bf16(
                af[ks], *(const bf16x8*)(Bq + (wx * 32 + m32) * KP + ks * 16 + half * 8),
                s, 0, 0, 0);

        // P = exp(S) -> PS (wave-private), accumulate partial l
#pragma unroll
        for (int r = 0; r < 16; r++) {
            int rowp = (r & 3) + 8 * (r >> 2) + 4 * half;
            float p = __expf(s[r]);
            lsum[r] += p;
            PS[(wa * 32 + rowp) * QTS + wx * 32 + m32] = (__bf16)p;
        }

        // O += P(32a x 32q of this wx) x QhT(32q x 160h)
#pragma unroll
        for (int kkL = 0; kkL < 2; kkL++) {
            bf16x8 pf = *(const bf16x8*)(PS + (wa * 32 + m32) * QTS + (wx * 2 + kkL) * 16 + half * 8);
#pragma unroll
            for (int t = 0; t < 5; t++)
                acc[t] = __builtin_amdgcn_mfma_f32_32x32x16_bf16(
                    pf, *(const bf16x8*)(Bv + (t * 32 + m32) * QTS + (wx * 2 + kkL) * 16 + half * 8),
                    acc[t], 0, 0, 0);
        }
        __syncthreads();  // drains prefetch; protects Buf reuse
    }

    // reduce partial l across the 32-lane half
#pragma unroll
    for (int r = 0; r < 16; r++) {
        float s = lsum[r];
#pragma unroll
        for (int m = 1; m < 32; m <<= 1) s += __shfl_xor(s, m, 64);
        lsum[r] = s;
    }
    const int part = qh * 2 + wx;
    __bf16* Ob = O + ((size_t)part * NROWS + b * LQ + a0 + wa * 32) * 160;
#pragma unroll
    for (int t = 0; t < 5; t++) {
        int h = t * 32 + m32;
#pragma unroll
        for (int r = 0; r < 16; r++) {
            int rowp = (r & 3) + 8 * (r >> 2) + 4 * half;
            Ob[(size_t)rowp * 160 + h] = (__bf16)acc[t][r];
        }
    }
    if (m32 == 0) {
        float* Lb = L + (size_t)part * NROWS + b * LQ + a0 + wa * 32;
#pragma unroll
        for (int r = 0; r < 16; r++) {
            int rowp = (r & 3) + 8 * (r >> 2) + 4 * half;
            Lb[rowp] = lsum[r];
        }
    }
}

// ---------------------------------------------------------------------------
// final: Hm = (sum of 4 O partials)/(sum of 4 l partials); Out = relu([Ah,Hm]@Wt+bt)
// ---------------------------------------------------------------------------
__global__ __launch_bounds__(256, 1) void final_mfma(
    const __bf16* __restrict__ AhB, const __bf16* __restrict__ O,
    const float* __restrict__ L, const __bf16* __restrict__ Wt12,
    const float* __restrict__ bt, float* __restrict__ Out)
{
    __shared__ __align__(16) __bf16 AS[64 * KP];          // 21504 B
    __shared__ __align__(16) __bf16 HS[64 * KP];          // 21504 B
    __shared__ __align__(16) __bf16 WtS[2 * 160 * KP];    // 107520 B
    const int tid = threadIdx.x;
    const int w = tid >> 6, lane = tid & 63;
    const int m32 = lane & 31, half = lane >> 5;
    const int r0 = blockIdx.x * 64;

    stage_flat(AhB + (size_t)r0 * KP, AS, 21504, w, lane);
    stage_flat(Wt12, WtS, 107520, w, lane);

    // combine 4 partials -> HS
    {
        int rhat = tid >> 2, qq = tid & 3;
        int grow = r0 + rhat;
        float inv = 1.f / (L[grow] + L[NROWS + grow] + L[2 * NROWS + grow] + L[3 * NROWS + grow]);
#pragma unroll
        for (int k = 0; k < 5; k++) {
            float sum[8];
#pragma unroll
            for (int j = 0; j < 8; j++) sum[j] = 0.f;
#pragma unroll
            for (int p = 0; p < 4; p++) {
                bf16x8 x = *(const bf16x8*)(O + ((size_t)p * NROWS + grow) * 160 + qq * 40 + k * 8);
#pragma unroll
                for (int j = 0; j < 8; j++) sum[j] += (float)x[j];
            }
            bf16x8 hv;
#pragma unroll
            for (int j = 0; j < 8; j++) hv[j] = (__bf16)(sum[j] * inv);
            *(bf16x8*)(HS + rhat * KP + qq * 40 + k * 8) = hv;
        }
    }
    __syncthreads();

    const int m = w & 1, th = w >> 1;
    const int tbase = th ? 3 : 0, tn = th ? 2 : 3;
    f32x16 acc[3];
#pragma unroll
    for (int i = 0; i < 3; i++) acc[i] = z16();

    for (int ch = 0; ch < 2; ch++) {
        const __bf16* src = ch ? HS : AS;
        for (int ks = 0; ks < 10; ks++) {
            bf16x8 af = *(const bf16x8*)(src + (m * 32 + m32) * KP + ks * 16 + half * 8);
#pragma unroll
            for (int ti = 0; ti < 3; ti++) {
                if (ti < tn) {
                    int t = tbase + ti;
                    acc[ti] = __builtin_amdgcn_mfma_f32_32x32x16_bf16(
                        af, *(const bf16x8*)(WtS + (ch * 160 + t * 32 + m32) * KP + ks * 16 + half * 8),
                        acc[ti], 0, 0, 0);
                }
            }
        }
    }

#pragma unroll
    for (int ti = 0; ti < 3; ti++) {
        if (ti < tn) {
            int t = tbase + ti;
            int h = t * 32 + m32;
            if (h < HHH) {
                float bth = bt[h];
#pragma unroll
                for (int r = 0; r < 16; r++) {
                    int rowp = (r & 3) + 8 * (r >> 2) + 4 * half;
                    float v = acc[ti][r] + bth;
                    Out[(size_t)(r0 + m * 32 + rowp) * HHH + h] = v > 0.f ? v : 0.f;
                }
            }
        }
    }
}

// ---------------------------------------------------------------------------
extern "C" void kernel_launch(void* const* d_in, const int* in_sizes, int n_in,
                              void* d_out, int out_size, void* d_ws, size_t ws_size,
                              hipStream_t stream)
{
    const float* Q  = (const float*)d_in[0];
    const float* A  = (const float*)d_in[1];
    const float* Wi = (const float*)d_in[2];
    const float* Wu = (const float*)d_in[3];
    const float* Wg = (const float*)d_in[4];
    const float* Wt = (const float*)d_in[5];
    const float* bi = (const float*)d_in[6];
    const float* bu = (const float*)d_in[7];
    const float* bg = (const float*)d_in[8];
    const float* bt = (const float*)d_in[9];
    float* out = (float*)d_out;

    char* ws = (char*)d_ws;
    __bf16* Slab = (__bf16*)(ws);                    // 11,534,336 B
    __bf16* AhB  = (__bf16*)(ws + 11534336);         //  5,505,024 B
    __bf16* Op   = (__bf16*)(ws + 17039360);         // 20,971,520 B (4 partials)
    float*  Lp   = (float*) (ws + 38010880);         //    262,144 B (4 partials)
    __bf16* WiC  = (__bf16*)(ws + 38273024);         //    108,544 B
    __bf16* WuC  = (__bf16*)(ws + 38381568);         //    108,544 B
    __bf16* WgT  = (__bf16*)(ws + 38490112);         //     54,272 B
    __bf16* Wt12 = (__bf16*)(ws + 38544384);         //    107,520 B

    convert_weights<<<dim3(212, 4), 256, 0, stream>>>(Wi, Wu, Wg, Wt,
                                                      WiC, WuC, WgT, Wt12);
    gatep<<<dim3(NROWS / 128, 2), 512, 0, stream>>>(Q, A, WiC, WuC, WgT,
                                                    bi, bu, bg, AhB, Slab);
    attn_mfma<<<dim3(16, BB, 2), 512, 0, stream>>>(Slab, AhB, Op, Lp);
    final_mfma<<<NROWS / 64, 256, 0, stream>>>(AhB, Op, Lp, Wt12, bt, out);
}

// Round 8
// 161.418 us; speedup vs baseline: 9.2851x; 1.0362x over previous
//
#include <hip/hip_runtime.h>
#include <math.h>

#define BB 8
#define LQ 2048
#define DD 300
#define HHH 150
#define NROWS (BB * LQ)

#define KP 168          // row stride (elems) for AhB / Qg / W rows (336 B)
#define QTS 72          // QhT q-stride and PS stride (144 B)
#define WCE 27136       // padded elems per W chunk (54,272 B; multiple of 1024)
#define SLAB_B 45056    // per-(b,qt) slab: [Qg 64x168 | pad 512B | QhT 160x72]
#define SLAB_E 22528
#define QHT_OFF_E 11008

typedef __bf16 bf16x8 __attribute__((ext_vector_type(8)));
typedef __bf16 bf16x4 __attribute__((ext_vector_type(4)));
typedef float f32x16 __attribute__((ext_vector_type(16)));

__device__ __forceinline__ void gl_lds16(const void* g, void* l) {
    __builtin_amdgcn_global_load_lds(
        (const __attribute__((address_space(1))) void*)g,
        (__attribute__((address_space(3))) void*)l,
        16, 0, 0);
}
// flat async global->LDS copy, 4-wave (256-thr) blocks
__device__ __forceinline__ void stage_flat(const void* g, void* l, int bytes,
                                           int w, int lane) {
    for (int ofs = w * 1024; ofs < bytes; ofs += 4096)
        gl_lds16((const char*)g + ofs + lane * 16, (char*)l + ofs);
}
// flat async global->LDS copy, 8-wave (512-thr) blocks
__device__ __forceinline__ void stage_flat8(const void* g, void* l, int bytes,
                                            int w, int lane) {
    for (int ofs = w * 1024; ofs < bytes; ofs += 8192)
        gl_lds16((const char*)g + ofs + lane * 16, (char*)l + ofs);
}
__device__ __forceinline__ f32x16 z16() {
    f32x16 v;
#pragma unroll
    for (int i = 0; i < 16; i++) v[i] = 0.f;
    return v;
}
__device__ __forceinline__ bf16x8 cvt8(float4 u, float4 v) {
    return (bf16x8){(__bf16)u.x, (__bf16)u.y, (__bf16)u.z, (__bf16)u.w,
                    (__bf16)v.x, (__bf16)v.y, (__bf16)v.z, (__bf16)v.w};
}

// ---------------------------------------------------------------------------
// Weight conversion. z=0/1: WiC/WuC [2 chunks][160h][168k]; z=2: WgT; z=3: Wt12.
// ---------------------------------------------------------------------------
__global__ __launch_bounds__(256) void convert_weights(
    const float* __restrict__ Wi, const float* __restrict__ Wu,
    const float* __restrict__ Wg, const float* __restrict__ Wt,
    __bf16* __restrict__ WiC, __bf16* __restrict__ WuC,
    __bf16* __restrict__ WgT, __bf16* __restrict__ Wt12)
{
    const int z = blockIdx.y;
    const int i = blockIdx.x * 256 + threadIdx.x;
    if (z < 2) {
        if (i >= 2 * WCE) return;
        int c = i / WCE, rem = i - c * WCE;
        float v = 0.f;
        if (rem < 160 * KP) {
            int h = rem / KP, kc = rem - h * KP;
            int d = c * 160 + kc;
            if (kc < 160 && d < DD && h < HHH) v = (z ? Wu : Wi)[(size_t)d * HHH + h];
        }
        (z ? WuC : WiC)[i] = (__bf16)v;
    } else if (z == 2) {
        if (i >= WCE) return;
        float v = 0.f;
        if (i < 160 * KP) {
            int h = i / KP, kc = i - h * KP;
            if (kc < HHH && h < HHH) v = Wg[(size_t)kc * HHH + h];
        }
        WgT[i] = (__bf16)v;
    } else {
        if (i >= 2 * 160 * KP) return;
        int c = i / (160 * KP), rem = i - c * (160 * KP);
        int h = rem / KP, kc = rem - h * KP;
        float v = (kc < HHH && h < HHH) ? Wt[(size_t)(c * HHH + kc) * HHH + h] : 0.f;
        Wt12[i] = (__bf16)v;
    }
}

// ---------------------------------------------------------------------------
// gatep v3: 512 thr / 8 waves (2 per SIMD). Wave (wm = w&3, wn = w>>2):
// rows wm*32..+31, h-tiles tof..tof+tn-1 (3/2 ragged split).
// z=1: Ah = gate(A) -> AhB.  z=0: Qh on-chip -> slab Qg + slab QhT.
// ---------------------------------------------------------------------------
__global__ __launch_bounds__(512, 2) void gatep(
    const float* __restrict__ Q, const float* __restrict__ A,
    const __bf16* __restrict__ WiC, const __bf16* __restrict__ WuC,
    const __bf16* __restrict__ WgT,
    const float* __restrict__ bi, const float* __restrict__ bu,
    const float* __restrict__ bg,
    __bf16* __restrict__ AhB, __bf16* __restrict__ Slab)
{
    __shared__ __align__(16) __bf16 WB[2][WCE];      // 108,544 B
    __shared__ __align__(16) __bf16 QhA[128 * KP];   //  43,008 B
    const int tid = threadIdx.x;
    const int w = tid >> 6, lane = tid & 63;
    const int m32 = lane & 31, half = lane >> 5;
    const int wm = w & 3, wn = w >> 2;
    const int tof = wn ? 3 : 0, tn = wn ? 2 : 3;
    const int z = blockIdx.y;
    const int r0 = blockIdx.x * 128;
    const float* X = z ? A : Q;

    stage_flat8(WiC, WB[0], 54272, w, lane);   // async; overlaps frag loads

    // ---- chunk-0 A-fragments straight from global (fp32 -> bf16) ----
    const float* xrow = X + (size_t)(r0 + wm * 32 + m32) * DD + half * 8;
    bf16x8 af0[10], af1[10];
#pragma unroll
    for (int ks = 0; ks < 10; ks++) {
        float4 u = *(const float4*)(xrow + ks * 16);
        float4 v = *(const float4*)(xrow + ks * 16 + 4);
        af0[ks] = cvt8(u, v);
    }

    f32x16 ai[3], au[3];
#pragma unroll
    for (int t = 0; t < 3; t++) { ai[t] = z16(); au[t] = z16(); }

    __syncthreads();                                   // WB0 = Wi-c0 ready
    stage_flat8(WuC, WB[1], 54272, w, lane);

    // chunk-1 fragments (hidden under ai-c0 MFMA phase)
#pragma unroll
    for (int ks = 0; ks < 8; ks++) {
        float4 u = *(const float4*)(xrow + 160 + ks * 16);
        float4 v = *(const float4*)(xrow + 160 + ks * 16 + 4);
        af1[ks] = cvt8(u, v);
    }
    {   // ks=8 tail: k>=300 masked (weights are zero there anyway)
        float4 u = *(const float4*)(xrow + 288);
        float4 v = (half == 0) ? *(const float4*)(xrow + 292) : (float4){0.f, 0.f, 0.f, 0.f};
        af1[8] = cvt8(u, v);
        af1[9] = (bf16x8){(__bf16)0.f, (__bf16)0.f, (__bf16)0.f, (__bf16)0.f,
                          (__bf16)0.f, (__bf16)0.f, (__bf16)0.f, (__bf16)0.f};
    }

    for (int ks = 0; ks < 10; ks++)
#pragma unroll
        for (int ti = 0; ti < 3; ti++)
            if (ti < tn)
                ai[ti] = __builtin_amdgcn_mfma_f32_32x32x16_bf16(
                    af0[ks], *(const bf16x8*)(WB[0] + ((tof + ti) * 32 + m32) * KP + ks * 16 + half * 8),
                    ai[ti], 0, 0, 0);
    __syncthreads();                                   // WB1 = Wu-c0 ready
    stage_flat8(WiC + WCE, WB[0], 54272, w, lane);
    for (int ks = 0; ks < 10; ks++)
#pragma unroll
        for (int ti = 0; ti < 3; ti++)
            if (ti < tn)
                au[ti] = __builtin_amdgcn_mfma_f32_32x32x16_bf16(
                    af0[ks], *(const bf16x8*)(WB[1] + ((tof + ti) * 32 + m32) * KP + ks * 16 + half * 8),
                    au[ti], 0, 0, 0);
    __syncthreads();                                   // WB0 = Wi-c1 ready
    stage_flat8(WuC + WCE, WB[1], 54272, w, lane);
    for (int ks = 0; ks < 10; ks++)
#pragma unroll
        for (int ti = 0; ti < 3; ti++)
            if (ti < tn)
                ai[ti] = __builtin_amdgcn_mfma_f32_32x32x16_bf16(
                    af1[ks], *(const bf16x8*)(WB[0] + ((tof + ti) * 32 + m32) * KP + ks * 16 + half * 8),
                    ai[ti], 0, 0, 0);
    __syncthreads();                                   // WB1 = Wu-c1 ready
    if (z == 0) stage_flat8(WgT, WB[0], 54272, w, lane);  // prefetch Wg
    for (int ks = 0; ks < 10; ks++)
#pragma unroll
        for (int ti = 0; ti < 3; ti++)
            if (ti < tn)
                au[ti] = __builtin_amdgcn_mfma_f32_32x32x16_bf16(
                    af1[ks], *(const bf16x8*)(WB[1] + ((tof + ti) * 32 + m32) * KP + ks * 16 + half * 8),
                    au[ti], 0, 0, 0);

    // ---- gate epilogue ----
#pragma unroll
    for (int ti = 0; ti < 3; ti++) {
        if (ti >= tn) continue;
        int h = (tof + ti) * 32 + m32;
        int hc = h < HHH ? h : 0;
        float bih = bi[hc], buh = bu[hc];
#pragma unroll
        for (int r = 0; r < 16; r++) {
            float v = 0.f;
            if (h < HHH) {
                float xi = ai[ti][r] + bih, xu = au[ti][r] + buh;
                float s = 1.f / (1.f + __expf(-xi));
                float tt = 1.f - 2.f / (1.f + __expf(2.f * xu));
                v = s * tt;
            }
            ai[ti][r] = v;
        }
    }

    if (z) {  // A-side: write AhB and exit
#pragma unroll
        for (int ti = 0; ti < 3; ti++) {
            if (ti >= tn) continue;
            int h = (tof + ti) * 32 + m32;
#pragma unroll
            for (int r = 0; r < 16; r++) {
                int rowp = (r & 3) + 8 * (r >> 2) + 4 * half;
                AhB[(size_t)(r0 + wm * 32 + rowp) * KP + h] = (__bf16)ai[ti][r];
            }
        }
        return;
    }

    // ---- Q-side: Qh -> LDS (rows shared across wn halves) ----
#pragma unroll
    for (int ti = 0; ti < 3; ti++) {
        if (ti >= tn) continue;
        int h = (tof + ti) * 32 + m32;
#pragma unroll
        for (int r = 0; r < 16; r++) {
            int rowp = (r & 3) + 8 * (r >> 2) + 4 * half;
            QhA[(wm * 32 + rowp) * KP + h] = (__bf16)ai[ti][r];
        }
    }
    __syncthreads();   // QhA visible block-wide; Wg in WB0 ready

    bf16x8 afq[10];
#pragma unroll
    for (int ks = 0; ks < 10; ks++)
        afq[ks] = *(const bf16x8*)(QhA + (wm * 32 + m32) * KP + ks * 16 + half * 8);

    f32x16 qg[3];
#pragma unroll
    for (int t = 0; t < 3; t++) qg[t] = z16();
    for (int ks = 0; ks < 10; ks++)
#pragma unroll
        for (int ti = 0; ti < 3; ti++)
            if (ti < tn)
                qg[ti] = __builtin_amdgcn_mfma_f32_32x32x16_bf16(
                    afq[ks], *(const bf16x8*)(WB[0] + ((tof + ti) * 32 + m32) * KP + ks * 16 + half * 8),
                    qg[ti], 0, 0, 0);

    const int b = r0 >> 11, qt0 = (r0 & 2047) >> 6;
#pragma unroll
    for (int ti = 0; ti < 3; ti++) {
        if (ti >= tn) continue;
        int h = (tof + ti) * 32 + m32;
        int hc = h < HHH ? h : 0;
        float bgh = bg[hc];
#pragma unroll
        for (int r = 0; r < 16; r++) {
            int rowp = (r & 3) + 8 * (r >> 2) + 4 * half;
            int q = (r0 & 2047) + wm * 32 + rowp;
            float v = (h < HHH) ? (qg[ti][r] + bgh) : 0.f;
            Slab[(size_t)(b * 32 + (q >> 6)) * SLAB_E + (q & 63) * KP + h] = (__bf16)v;
        }
    }

    // QhT transpose-scatter (512 threads)
    {
        const int jl = tid & 63, tile = (tid >> 6) & 1, hgrp = tid >> 7;
        for (int hseg = hgrp; hseg < 20; hseg += 4) {
            bf16x8 vv = *(const bf16x8*)(QhA + (tile * 64 + jl) * KP + hseg * 8);
            __bf16* dst = Slab + (size_t)(b * 32 + qt0 + tile) * SLAB_E + QHT_OFF_E + jl;
#pragma unroll
            for (int e = 0; e < 8; e++)
                dst[(hseg * 8 + e) * QTS] = vv[e];
        }
    }
}

// ---------------------------------------------------------------------------
// attn v4: 256-row a-tiles, 512 thr / 8 waves (2/SIMD). Wave w owns a-rows
// w*32..+31 for both S (32a x 64q) and PV (64q -> 160h). Grid (8, BB, 4 qparts);
// each block streams 8 q-tiles, staging one 45 KB slab per iter (prefetched).
// PS fully wave-private. O/l written as partial qp (4 partials, as before).
// ---------------------------------------------------------------------------
__global__ __launch_bounds__(512, 2) void attn_mfma(
    const __bf16* __restrict__ Slab, const __bf16* __restrict__ AhB,
    __bf16* __restrict__ O, float* __restrict__ L)
{
    __shared__ __align__(16) __bf16 Buf[2][SLAB_E];   // 90,112 B
    __shared__ __align__(16) __bf16 PS[256 * QTS];    // 36,864 B
    const int tid = threadIdx.x;
    const int w = tid >> 6, lane = tid & 63;
    const int m32 = lane & 31, half = lane >> 5;
    const int b = blockIdx.y, qp = blockIdx.z;
    const int a0 = blockIdx.x * 256;

    const char* slabBase = (const char*)Slab + (size_t)(b * 32 + qp * 8) * SLAB_B;
    stage_flat8(slabBase, Buf[0], SLAB_B, w, lane);

    // A-fragments from global (row gather, once per kernel; overlaps staging)
    const __bf16* arow = AhB + (size_t)(b * LQ + a0 + w * 32 + m32) * KP + half * 8;
    bf16x8 af[10];
#pragma unroll
    for (int ks = 0; ks < 10; ks++)
        af[ks] = *(const bf16x8*)(arow + ks * 16);

    float lsum[16];
#pragma unroll
    for (int r = 0; r < 16; r++) lsum[r] = 0.f;
    f32x16 acc[5];
#pragma unroll
    for (int t = 0; t < 5; t++) acc[t] = z16();
    __syncthreads();

    for (int qt = 0; qt < 8; qt++) {
        const int cur = qt & 1;
        if (qt < 7)
            stage_flat8(slabBase + (size_t)(qt + 1) * SLAB_B, Buf[cur ^ 1], SLAB_B, w, lane);
        const __bf16* Bq = Buf[cur];
        const __bf16* Bv = Buf[cur] + QHT_OFF_E;

        // S = Ah(32a) x Qg(64q), K=160 -> two 32x32 C-tiles (q 0..31, 32..63)
        f32x16 s0 = z16(), s1 = z16();
        for (int ks = 0; ks < 10; ks++) {
            bf16x8 b0 = *(const bf16x8*)(Bq + m32 * KP + ks * 16 + half * 8);
            bf16x8 b1 = *(const bf16x8*)(Bq + (32 + m32) * KP + ks * 16 + half * 8);
            s0 = __builtin_amdgcn_mfma_f32_32x32x16_bf16(af[ks], b0, s0, 0, 0, 0);
            s1 = __builtin_amdgcn_mfma_f32_32x32x16_bf16(af[ks], b1, s1, 0, 0, 0);
        }

        // P = exp(S) -> PS (wave-private rows), accumulate l
#pragma unroll
        for (int r = 0; r < 16; r++) {
            int rowp = (r & 3) + 8 * (r >> 2) + 4 * half;
            float p0 = __expf(s0[r]);
            float p1 = __expf(s1[r]);
            PS[(w * 32 + rowp) * QTS + m32] = (__bf16)p0;
            PS[(w * 32 + rowp) * QTS + 32 + m32] = (__bf16)p1;
            lsum[r] += p0 + p1;
        }

        // O += P(32a x 64q) x QhT(64q x 160h)
#pragma unroll
        for (int kk = 0; kk < 4; kk++) {
            bf16x8 pf = *(const bf16x8*)(PS + (w * 32 + m32) * QTS + kk * 16 + half * 8);
#pragma unroll
            for (int t = 0; t < 5; t++)
                acc[t] = __builtin_amdgcn_mfma_f32_32x32x16_bf16(
                    pf, *(const bf16x8*)(Bv + (t * 32 + m32) * QTS + kk * 16 + half * 8),
                    acc[t], 0, 0, 0);
        }
        __syncthreads();  // drains prefetch; protects Buf reuse
    }

    // reduce partial l across the 32-lane q direction
#pragma unroll
    for (int r = 0; r < 16; r++) {
        float s = lsum[r];
#pragma unroll
        for (int m = 1; m < 32; m <<= 1) s += __shfl_xor(s, m, 64);
        lsum[r] = s;
    }
    __bf16* Ob = O + ((size_t)qp * NROWS + b * LQ + a0 + w * 32) * 160;
#pragma unroll
    for (int t = 0; t < 5; t++) {
        int h = t * 32 + m32;
#pragma unroll
        for (int r = 0; r < 16; r++) {
            int rowp = (r & 3) + 8 * (r >> 2) + 4 * half;
            Ob[(size_t)rowp * 160 + h] = (__bf16)acc[t][r];
        }
    }
    if (m32 == 0) {
        float* Lb = L + (size_t)qp * NROWS + b * LQ + a0 + w * 32;
#pragma unroll
        for (int r = 0; r < 16; r++) {
            int rowp = (r & 3) + 8 * (r >> 2) + 4 * half;
            Lb[rowp] = lsum[r];
        }
    }
}

// ---------------------------------------------------------------------------
// final: Hm = (sum of 4 O partials)/(sum of 4 l partials); Out = relu([Ah,Hm]@Wt+bt)
// ---------------------------------------------------------------------------
__global__ __launch_bounds__(256, 1) void final_mfma(
    const __bf16* __restrict__ AhB, const __bf16* __restrict__ O,
    const float* __restrict__ L, const __bf16* __restrict__ Wt12,
    const float* __restrict__ bt, float* __restrict__ Out)
{
    __shared__ __align__(16) __bf16 AS[64 * KP];          // 21504 B
    __shared__ __align__(16) __bf16 HS[64 * KP];          // 21504 B
    __shared__ __align__(16) __bf16 WtS[2 * 160 * KP];    // 107520 B
    const int tid = threadIdx.x;
    const int w = tid >> 6, lane = tid & 63;
    const int m32 = lane & 31, half = lane >> 5;
    const int r0 = blockIdx.x * 64;

    stage_flat(AhB + (size_t)r0 * KP, AS, 21504, w, lane);
    stage_flat(Wt12, WtS, 107520, w, lane);

    // combine 4 partials -> HS
    {
        int rhat = tid >> 2, qq = tid & 3;
        int grow = r0 + rhat;
        float inv = 1.f / (L[grow] + L[NROWS + grow] + L[2 * NROWS + grow] + L[3 * NROWS + grow]);
#pragma unroll
        for (int k = 0; k < 5; k++) {
            float sum[8];
#pragma unroll
            for (int j = 0; j < 8; j++) sum[j] = 0.f;
#pragma unroll
            for (int p = 0; p < 4; p++) {
                bf16x8 x = *(const bf16x8*)(O + ((size_t)p * NROWS + grow) * 160 + qq * 40 + k * 8);
#pragma unroll
                for (int j = 0; j < 8; j++) sum[j] += (float)x[j];
            }
            bf16x8 hv;
#pragma unroll
            for (int j = 0; j < 8; j++) hv[j] = (__bf16)(sum[j] * inv);
            *(bf16x8*)(HS + rhat * KP + qq * 40 + k * 8) = hv;
        }
    }
    __syncthreads();

    const int m = w & 1, th = w >> 1;
    const int tbase = th ? 3 : 0, tn = th ? 2 : 3;
    f32x16 acc[3];
#pragma unroll
    for (int i = 0; i < 3; i++) acc[i] = z16();

    for (int ch = 0; ch < 2; ch++) {
        const __bf16* src = ch ? HS : AS;
        for (int ks = 0; ks < 10; ks++) {
            bf16x8 af = *(const bf16x8*)(src + (m * 32 + m32) * KP + ks * 16 + half * 8);
#pragma unroll
            for (int ti = 0; ti < 3; ti++) {
                if (ti < tn) {
                    int t = tbase + ti;
                    acc[ti] = __builtin_amdgcn_mfma_f32_32x32x16_bf16(
                        af, *(const bf16x8*)(WtS + (ch * 160 + t * 32 + m32) * KP + ks * 16 + half * 8),
                        acc[ti], 0, 0, 0);
                }
            }
        }
    }

#pragma unroll
    for (int ti = 0; ti < 3; ti++) {
        if (ti < tn) {
            int t = tbase + ti;
            int h = t * 32 + m32;
            if (h < HHH) {
                float bth = bt[h];
#pragma unroll
                for (int r = 0; r < 16; r++) {
                    int rowp = (r & 3) + 8 * (r >> 2) + 4 * half;
                    float v = acc[ti][r] + bth;
                    Out[(size_t)(r0 + m * 32 + rowp) * HHH + h] = v > 0.f ? v : 0.f;
                }
            }
        }
    }
}

// ---------------------------------------------------------------------------
extern "C" void kernel_launch(void* const* d_in, const int* in_sizes, int n_in,
                              void* d_out, int out_size, void* d_ws, size_t ws_size,
                              hipStream_t stream)
{
    const float* Q  = (const float*)d_in[0];
    const float* A  = (const float*)d_in[1];
    const float* Wi = (const float*)d_in[2];
    const float* Wu = (const float*)d_in[3];
    const float* Wg = (const float*)d_in[4];
    const float* Wt = (const float*)d_in[5];
    const float* bi = (const float*)d_in[6];
    const float* bu = (const float*)d_in[7];
    const float* bg = (const float*)d_in[8];
    const float* bt = (const float*)d_in[9];
    float* out = (float*)d_out;

    char* ws = (char*)d_ws;
    __bf16* Slab = (__bf16*)(ws);                    // 11,534,336 B
    __bf16* AhB  = (__bf16*)(ws + 11534336);         //  5,505,024 B
    __bf16* Op   = (__bf16*)(ws + 17039360);         // 20,971,520 B (4 partials)
    float*  Lp   = (float*) (ws + 38010880);         //    262,144 B (4 partials)
    __bf16* WiC  = (__bf16*)(ws + 38273024);         //    108,544 B
    __bf16* WuC  = (__bf16*)(ws + 38381568);         //    108,544 B
    __bf16* WgT  = (__bf16*)(ws + 38490112);         //     54,272 B
    __bf16* Wt12 = (__bf16*)(ws + 38544384);         //    107,520 B

    convert_weights<<<dim3(212, 4), 256, 0, stream>>>(Wi, Wu, Wg, Wt,
                                                      WiC, WuC, WgT, Wt12);
    gatep<<<dim3(NROWS / 128, 2), 512, 0, stream>>>(Q, A, WiC, WuC, WgT,
                                                    bi, bu, bg, AhB, Slab);
    attn_mfma<<<dim3(8, BB, 4), 512, 0, stream>>>(Slab, AhB, Op, Lp);
    final_mfma<<<NROWS / 64, 256, 0, stream>>>(AhB, Op, Lp, Wt12, bt, out);
}